// Round 1
// baseline (1248.306 us; speedup 1.0000x reference)
//
#include <hip/hip_runtime.h>
#include <math.h>

#define NN 100000
#define EE 1600000
#define HH 128
#define GG 512
#define OUTD 10

// ---------------- init ----------------
__global__ void init_kernel(int* deg, int* gs, int* ge, float* out) {
  int i = blockIdx.x * 256 + threadIdx.x;
  if (i < NN) deg[i] = 1;            // self-loop
  if (i < GG) { gs[i] = 0; ge[i] = 0; }
  if (i == 0) out[GG * OUTD] = 0.0f; // the scalar second output
}

// ---------------- degree count ----------------
__global__ void count_kernel(const int* __restrict__ ei, int* __restrict__ deg) {
  int e = blockIdx.x * 256 + threadIdx.x;
  if (e >= EE) return;
  atomicAdd(&deg[ei[EE + e]], 1);    // col = ei[1][e]
}

// ---------------- exclusive scan of (deg-1), 2048 elems/block ----------------
__global__ __launch_bounds__(256) void scan1_kernel(const int* __restrict__ deg,
                                                    int* __restrict__ offs,
                                                    int* __restrict__ bsums) {
  __shared__ int ts[256];
  int t = threadIdx.x;
  int base = blockIdx.x * 2048 + t * 8;
  int v[8]; int s = 0;
#pragma unroll
  for (int i = 0; i < 8; i++) {
    int idx = base + i;
    int c = (idx < NN) ? (deg[idx] - 1) : 0;
    v[i] = s; s += c;
  }
  ts[t] = s;
  __syncthreads();
  for (int off = 1; off < 256; off <<= 1) {
    int x = (t >= off) ? ts[t - off] : 0;
    __syncthreads();
    ts[t] += x;
    __syncthreads();
  }
  int excl = (t == 0) ? 0 : ts[t - 1];
  if (t == 255) bsums[blockIdx.x] = ts[255];
#pragma unroll
  for (int i = 0; i < 8; i++) {
    int idx = base + i;
    if (idx < NN) offs[idx] = excl + v[i];
  }
}

__global__ void scan2_kernel(int* bsums, int nb) {
  if (threadIdx.x == 0 && blockIdx.x == 0) {
    int s = 0;
    for (int b = 0; b < nb; b++) { int x = bsums[b]; bsums[b] = s; s += x; }
  }
}

__global__ void scan3_kernel(const int* __restrict__ deg, int* __restrict__ offs,
                             int* __restrict__ cursor, float* __restrict__ dis,
                             const int* __restrict__ bsums) {
  int i = blockIdx.x * 256 + threadIdx.x;
  if (i >= NN) return;
  int o = offs[i] + bsums[i >> 11];
  offs[i] = o; cursor[i] = o;
  dis[i] = rsqrtf((float)deg[i]);    // deg >= 1 always
  if (i == NN - 1) offs[NN] = EE;
}

// ---------------- CSR fill ----------------
__global__ void fill_kernel(const int* __restrict__ ei, int* __restrict__ cursor,
                            int* __restrict__ csr_src, float* __restrict__ csr_w,
                            const float* __restrict__ dis) {
  int e = blockIdx.x * 256 + threadIdx.x;
  if (e >= EE) return;
  int r = ei[e];
  int c = ei[EE + e];
  int slot = atomicAdd(&cursor[c], 1);
  csr_src[slot] = r;
  csr_w[slot] = dis[r];
}

// ---------------- dense GEMM [nrows,128] @ [128,128] ----------------
template <int BIAS_RELU>
__global__ __launch_bounds__(256) void gemm_kernel(const float* __restrict__ A,
                                                   const float* __restrict__ W,
                                                   const float* __restrict__ bias,
                                                   float* __restrict__ out, int nrows) {
  __shared__ float xs[64][128];
  __shared__ float ws[128][128];
  int t = threadIdx.x;
  int row0 = blockIdx.x * 64;
  const float4* W4 = (const float4*)W;
  float4* ws4 = (float4*)&ws[0][0];
#pragma unroll
  for (int i = 0; i < 16; i++) ws4[t + 256 * i] = W4[t + 256 * i];
  const float4* A4 = (const float4*)A;
  float4* xs4 = (float4*)&xs[0][0];
#pragma unroll
  for (int i = 0; i < 8; i++) {
    int idx = t + 256 * i;          // 0..2047 ; row = idx>>5 (32 float4 per row)
    int r = row0 + (idx >> 5);
    float4 val = make_float4(0.f, 0.f, 0.f, 0.f);
    if (r < nrows) val = A4[(size_t)r * 32 + (idx & 31)];
    xs4[idx] = val;
  }
  __syncthreads();
  int tcg = t & 31;   // cols tcg*4 .. +3
  int trg = t >> 5;   // rows trg*8 .. +7
  float acc[8][4];
#pragma unroll
  for (int i = 0; i < 8; i++)
#pragma unroll
    for (int j = 0; j < 4; j++) acc[i][j] = 0.f;

#pragma unroll 4
  for (int kq = 0; kq < 32; ++kq) {
    float4 a[8], b[4];
#pragma unroll
    for (int i = 0; i < 8; i++) a[i] = *(const float4*)&xs[trg * 8 + i][kq * 4];
#pragma unroll
    for (int j = 0; j < 4; j++) b[j] = *(const float4*)&ws[kq * 4 + j][tcg * 4];
#pragma unroll
    for (int i = 0; i < 8; i++) {
      acc[i][0] += a[i].x * b[0].x + a[i].y * b[1].x + a[i].z * b[2].x + a[i].w * b[3].x;
      acc[i][1] += a[i].x * b[0].y + a[i].y * b[1].y + a[i].z * b[2].y + a[i].w * b[3].y;
      acc[i][2] += a[i].x * b[0].z + a[i].y * b[1].z + a[i].z * b[2].z + a[i].w * b[3].z;
      acc[i][3] += a[i].x * b[0].w + a[i].y * b[1].w + a[i].z * b[2].w + a[i].w * b[3].w;
    }
  }
#pragma unroll
  for (int i = 0; i < 8; i++) {
    int r = row0 + trg * 8 + i;
    if (r >= nrows) continue;
    float4 v = make_float4(acc[i][0], acc[i][1], acc[i][2], acc[i][3]);
    if (BIAS_RELU) {
      v.x = fmaxf(v.x + bias[tcg * 4 + 0], 0.f);
      v.y = fmaxf(v.y + bias[tcg * 4 + 1], 0.f);
      v.z = fmaxf(v.z + bias[tcg * 4 + 2], 0.f);
      v.w = fmaxf(v.w + bias[tcg * 4 + 3], 0.f);
    }
    *(float4*)&out[(size_t)r * 128 + tcg * 4] = v;
  }
}

// ---------------- aggregation: out[c] = relu(sum_e w_e * t[src_e] + dc^2 t[c] + b) ----------------
__global__ void agg_kernel(const float* __restrict__ t, const int* __restrict__ offs,
                           const int* __restrict__ csr_src, const float* __restrict__ csr_w,
                           const float* __restrict__ dis, const float* __restrict__ bias,
                           float* __restrict__ out) {
  int c = blockIdx.x;
  int col = threadIdx.x;  // 128 threads
  float dc = dis[c];
  int s = offs[c], e = offs[c + 1];
  float acc = dc * dc * t[(size_t)c * 128 + col];
  for (int k = s; k < e; ++k) {
    int r = csr_src[k];
    float w = csr_w[k] * dc;
    acc += w * t[(size_t)r * 128 + col];
  }
  out[(size_t)c * 128 + col] = fmaxf(acc + bias[col], 0.f);
}

// ---------------- gate = ghidden . gW2 + gb2 ----------------
__global__ void gatedot_kernel(const float* __restrict__ gh, const float* __restrict__ gW2,
                               const float* __restrict__ gb2, float* __restrict__ gate) {
  int row = blockIdx.x * 4 + (threadIdx.x >> 6);
  int lane = threadIdx.x & 63;
  if (row >= NN) return;
  const float* r = gh + (size_t)row * 128;
  float v = r[lane] * gW2[lane] + r[64 + lane] * gW2[64 + lane];
#pragma unroll
  for (int o = 32; o > 0; o >>= 1) v += __shfl_down(v, o);
  if (lane == 0) gate[row] = v + gb2[0];
}

// ---------------- graph boundaries (batch sorted) ----------------
__global__ void bounds_kernel(const int* __restrict__ batch, int* gs, int* ge) {
  int i = blockIdx.x * 256 + threadIdx.x;
  if (i >= NN) return;
  int b = batch[i];
  if (i == 0 || batch[i - 1] != b) gs[b] = i;
  if (i == NN - 1 || batch[i + 1] != b) ge[b] = i + 1;
}

// ---------------- per-graph softmax + pool + MLP head ----------------
__global__ __launch_bounds__(256) void poolhead_kernel(
    const float* __restrict__ h, const float* __restrict__ gate,
    const int* __restrict__ gs, const int* __restrict__ ge,
    const float* __restrict__ lW1, const float* __restrict__ lb1,
    const float* __restrict__ lW2, const float* __restrict__ lb2,
    float* __restrict__ out) {
  int g = blockIdx.x;
  int t = threadIdx.x;
  int s = gs[g], e = ge[g];
  __shared__ float red[4];
  __shared__ float pacc[2][128];
  __shared__ float pooled[128];
  __shared__ float hid[128];
  int wid = t >> 6, lane = t & 63;

  // max
  float m = -3.0e38f;
  for (int i = s + t; i < e; i += 256) m = fmaxf(m, gate[i]);
#pragma unroll
  for (int o = 32; o > 0; o >>= 1) m = fmaxf(m, __shfl_xor(m, o));
  if (lane == 0) red[wid] = m;
  __syncthreads();
  m = fmaxf(fmaxf(red[0], red[1]), fmaxf(red[2], red[3]));
  __syncthreads();

  // sum of exp
  float ds_ = 0.f;
  for (int i = s + t; i < e; i += 256) ds_ += __expf(gate[i] - m);
#pragma unroll
  for (int o = 32; o > 0; o >>= 1) ds_ += __shfl_xor(ds_, o);
  if (lane == 0) red[wid] = ds_;
  __syncthreads();
  float denom = red[0] + red[1] + red[2] + red[3];

  // weighted pool
  int col = t & 127, half = t >> 7;
  float acc = 0.f;
  for (int i = s + half; i < e; i += 2)
    acc += __expf(gate[i] - m) * h[(size_t)i * 128 + col];
  pacc[half][col] = acc;
  __syncthreads();
  if (t < 128) {
    float p = (e > s) ? (pacc[0][t] + pacc[1][t]) / denom : 0.f;
    pooled[t] = p;
  }
  __syncthreads();

  // head: hid = relu(pooled @ lW1 + lb1)
  if (t < 128) {
    float hv = lb1[t];
    for (int k = 0; k < 128; k++) hv += pooled[k] * lW1[k * 128 + t];
    hid[t] = fmaxf(hv, 0.f);
  }
  __syncthreads();

  // logits = hid @ lW2 + lb2
  if (t < OUTD) {
    float acc2 = lb2[t];
    for (int k = 0; k < 128; k++) acc2 += hid[k] * lW2[k * OUTD + t];
    out[g * OUTD + t] = acc2;
  }
}

extern "C" void kernel_launch(void* const* d_in, const int* in_sizes, int n_in,
                              void* d_out, int out_size, void* d_ws, size_t ws_size,
                              hipStream_t stream) {
  const float* x   = (const float*)d_in[0];
  const int*   ei  = (const int*)d_in[1];
  const int* batch = (const int*)d_in[2];
  const float* W0  = (const float*)d_in[3];
  const float* b0  = (const float*)d_in[4];
  const float* W1  = (const float*)d_in[5];
  const float* b1  = (const float*)d_in[6];
  const float* W2  = (const float*)d_in[7];
  const float* b2  = (const float*)d_in[8];
  const float* gW1 = (const float*)d_in[9];
  const float* gb1 = (const float*)d_in[10];
  const float* gW2 = (const float*)d_in[11];
  const float* gb2 = (const float*)d_in[12];
  const float* lW1 = (const float*)d_in[13];
  const float* lb1 = (const float*)d_in[14];
  const float* lW2 = (const float*)d_in[15];
  const float* lb2 = (const float*)d_in[16];
  float* out = (float*)d_out;

  char* w = (char*)d_ws;
  auto alloc = [&](size_t bytes) {
    char* p = w;
    w += (bytes + 255) & ~(size_t)255;
    return p;
  };
  float* T     = (float*)alloc((size_t)NN * 128 * 4);
  float* HA    = (float*)alloc((size_t)NN * 128 * 4);
  float* HB    = (float*)alloc((size_t)NN * 128 * 4);
  int* deg     = (int*)alloc((size_t)NN * 4);
  int* offs    = (int*)alloc((size_t)(NN + 1) * 4);
  int* cursor  = (int*)alloc((size_t)NN * 4);
  float* dis   = (float*)alloc((size_t)NN * 4);
  int* csr_src = (int*)alloc((size_t)EE * 4);
  float* csr_w = (float*)alloc((size_t)EE * 4);
  float* gate  = (float*)alloc((size_t)NN * 4);
  int* bsums   = (int*)alloc(64 * 4);
  int* gs      = (int*)alloc(GG * 4);
  int* ge      = (int*)alloc(GG * 4);

  dim3 b256(256);
  init_kernel<<<dim3((NN + 255) / 256), b256, 0, stream>>>(deg, gs, ge, out);
  count_kernel<<<dim3((EE + 255) / 256), b256, 0, stream>>>(ei, deg);
  scan1_kernel<<<dim3(49), b256, 0, stream>>>(deg, offs, bsums);
  scan2_kernel<<<dim3(1), dim3(64), 0, stream>>>(bsums, 49);
  scan3_kernel<<<dim3((NN + 255) / 256), b256, 0, stream>>>(deg, offs, cursor, dis, bsums);
  fill_kernel<<<dim3((EE + 255) / 256), b256, 0, stream>>>(ei, cursor, csr_src, csr_w, dis);

  int gblocks = (NN + 63) / 64;
  // layer 0
  gemm_kernel<0><<<dim3(gblocks), b256, 0, stream>>>(x, W0, nullptr, T, NN);
  agg_kernel<<<dim3(NN), dim3(128), 0, stream>>>(T, offs, csr_src, csr_w, dis, b0, HA);
  // layer 1
  gemm_kernel<0><<<dim3(gblocks), b256, 0, stream>>>(HA, W1, nullptr, T, NN);
  agg_kernel<<<dim3(NN), dim3(128), 0, stream>>>(T, offs, csr_src, csr_w, dis, b1, HB);
  // layer 2
  gemm_kernel<0><<<dim3(gblocks), b256, 0, stream>>>(HB, W2, nullptr, T, NN);
  agg_kernel<<<dim3(NN), dim3(128), 0, stream>>>(T, offs, csr_src, csr_w, dis, b2, HA);

  // gate network
  gemm_kernel<1><<<dim3(gblocks), b256, 0, stream>>>(HA, gW1, gb1, T, NN);
  gatedot_kernel<<<dim3((NN + 3) / 4), b256, 0, stream>>>(T, gW2, gb2, gate);
  bounds_kernel<<<dim3((NN + 255) / 256), b256, 0, stream>>>(batch, gs, ge);
  poolhead_kernel<<<dim3(GG), b256, 0, stream>>>(HA, gate, gs, ge, lW1, lb1, lW2, lb2, out);
}

// Round 4
// 621.988 us; speedup vs baseline: 2.0070x; 2.0070x over previous
//
#include <hip/hip_runtime.h>
#include <math.h>

#define NN 100000
#define EE 1600000
#define HH 128
#define GG 512
#define OUTD 10

typedef _Float16 f16x2 __attribute__((ext_vector_type(2)));
typedef _Float16 f16x8 __attribute__((ext_vector_type(8)));
typedef float f32x4 __attribute__((ext_vector_type(4)));

// ---------------- init ----------------
__global__ void init_kernel(int* deg, int* gs, int* ge, float* out) {
  int i = blockIdx.x * 256 + threadIdx.x;
  if (i < NN) deg[i] = 1;            // self-loop
  if (i < GG) { gs[i] = 0; ge[i] = 0; }
  if (i == 0) out[GG * OUTD] = 0.0f; // the scalar second output
}

// ---------------- degree count ----------------
__global__ void count_kernel(const int* __restrict__ ei, int* __restrict__ deg) {
  int e = blockIdx.x * 256 + threadIdx.x;
  if (e >= EE) return;
  atomicAdd(&deg[ei[EE + e]], 1);    // col = ei[1][e]
}

// ---------------- exclusive scan of (deg-1), 2048 elems/block ----------------
__global__ __launch_bounds__(256) void scan1_kernel(const int* __restrict__ deg,
                                                    int* __restrict__ offs,
                                                    int* __restrict__ bsums) {
  __shared__ int ts[256];
  int t = threadIdx.x;
  int base = blockIdx.x * 2048 + t * 8;
  int v[8]; int s = 0;
#pragma unroll
  for (int i = 0; i < 8; i++) {
    int idx = base + i;
    int c = (idx < NN) ? (deg[idx] - 1) : 0;
    v[i] = s; s += c;
  }
  ts[t] = s;
  __syncthreads();
  for (int off = 1; off < 256; off <<= 1) {
    int x = (t >= off) ? ts[t - off] : 0;
    __syncthreads();
    ts[t] += x;
    __syncthreads();
  }
  int excl = (t == 0) ? 0 : ts[t - 1];
  if (t == 255) bsums[blockIdx.x] = ts[255];
#pragma unroll
  for (int i = 0; i < 8; i++) {
    int idx = base + i;
    if (idx < NN) offs[idx] = excl + v[i];
  }
}

__global__ void scan2_kernel(int* bsums, int nb) {
  if (threadIdx.x == 0 && blockIdx.x == 0) {
    int s = 0;
    for (int b = 0; b < nb; b++) { int x = bsums[b]; bsums[b] = s; s += x; }
  }
}

__global__ void scan3_kernel(const int* __restrict__ deg, int* __restrict__ offs,
                             int* __restrict__ cursor, float* __restrict__ dis,
                             const int* __restrict__ bsums) {
  int i = blockIdx.x * 256 + threadIdx.x;
  if (i >= NN) return;
  int o = offs[i] + bsums[i >> 11];
  offs[i] = o; cursor[i] = o;
  dis[i] = rsqrtf((float)deg[i]);    // deg >= 1 always
  if (i == NN - 1) offs[NN] = EE;
}

// ---------------- CSR fill ----------------
__global__ void fill_kernel(const int* __restrict__ ei, int* __restrict__ cursor,
                            int* __restrict__ csr_src, float* __restrict__ csr_w,
                            const float* __restrict__ dis) {
  int e = blockIdx.x * 256 + threadIdx.x;
  if (e >= EE) return;
  int r = ei[e];
  int c = ei[EE + e];
  int slot = atomicAdd(&cursor[c], 1);
  csr_src[slot] = r;
  csr_w[slot] = dis[r];
}

// ---------------- weight transpose + fp16 convert: Wt[m][c][k] = W_m[k][c] ----------------
__global__ void prep_kernel(const float* __restrict__ W0, const float* __restrict__ W1,
                            const float* __restrict__ W2, const float* __restrict__ gW1,
                            _Float16* __restrict__ Wt) {
  int idx = blockIdx.x * 256 + threadIdx.x;   // 4*128*128 = 65536
  int m = idx >> 14;
  int rem = idx & 16383;
  int c = rem >> 7;
  int k = rem & 127;
  const float* src = (m == 0) ? W0 : (m == 1) ? W1 : (m == 2) ? W2 : gW1;
  Wt[idx] = (_Float16)src[k * 128 + c];
}

// ---------------- MFMA GEMM: [nrows,128] @ [128,128] -> fp16 ----------------
// Wt is the transposed fp16 weight [col][k]. AF32: A is f32 (layer 0), else fp16.
template <int AF32, int BIAS_RELU>
__global__ __launch_bounds__(256) void gemm_kernel(const void* __restrict__ Av,
                                                   const _Float16* __restrict__ Wt,
                                                   const float* __restrict__ bias,
                                                   _Float16* __restrict__ out, int nrows) {
  __shared__ __align__(16) _Float16 wlds[128 * 136];  // padded stride 136 halves (272 B)
  int t = threadIdx.x;
  // stage Wt -> LDS (16B chunks; global chunk q == row q>>4, pos q&15)
  const uint4* src = (const uint4*)Wt;
#pragma unroll
  for (int i = 0; i < 8; i++) {
    int q = t + 256 * i;
    int c = q >> 4, p = q & 15;
    *(uint4*)&wlds[c * 136 + p * 8] = src[q];
  }
  __syncthreads();

  int wid = t >> 6, l = t & 63;
  int wr0 = blockIdx.x * 64 + wid * 16;
  int row = wr0 + (l & 15);
  bool valid = row < nrows;
  f16x8 zero8 = {(_Float16)0, (_Float16)0, (_Float16)0, (_Float16)0,
                 (_Float16)0, (_Float16)0, (_Float16)0, (_Float16)0};
  f16x8 af[4];
  if (AF32) {
    const float* ap = (const float*)Av + (size_t)row * 128;
#pragma unroll
    for (int kt = 0; kt < 4; kt++) {
      if (valid) {
        const float4* p4 = (const float4*)(ap + kt * 32 + (l >> 4) * 8);
        float4 u0 = p4[0], u1 = p4[1];
        f16x8 a;
        a[0] = (_Float16)u0.x; a[1] = (_Float16)u0.y; a[2] = (_Float16)u0.z; a[3] = (_Float16)u0.w;
        a[4] = (_Float16)u1.x; a[5] = (_Float16)u1.y; a[6] = (_Float16)u1.z; a[7] = (_Float16)u1.w;
        af[kt] = a;
      } else af[kt] = zero8;
    }
  } else {
    const _Float16* ap = (const _Float16*)Av + (size_t)row * 128;
#pragma unroll
    for (int kt = 0; kt < 4; kt++)
      af[kt] = valid ? *(const f16x8*)(ap + kt * 32 + (l >> 4) * 8) : zero8;
  }

  f32x4 acc[8] = {};
  int ko = (l >> 4) * 16;  // byte offset of this lane-group's k-chunk within a 64B kt block
#pragma unroll
  for (int n = 0; n < 8; n++) {
    int col = n * 16 + (l & 15);
    const char* base = (const char*)wlds + col * 272;
#pragma unroll
    for (int kt = 0; kt < 4; kt++) {
      f16x8 b = *(const f16x8*)(base + kt * 64 + ko);
      acc[n] = __builtin_amdgcn_mfma_f32_16x16x32_f16(af[kt], b, acc[n], 0, 0, 0);
    }
  }

#pragma unroll
  for (int n = 0; n < 8; n++) {
    int col = n * 16 + (l & 15);
    float bv = BIAS_RELU ? bias[col] : 0.f;
#pragma unroll
    for (int r = 0; r < 4; r++) {
      int orow = wr0 + (l >> 4) * 4 + r;
      if (orow < nrows) {
        float v = acc[n][r];
        if (BIAS_RELU) v = fmaxf(v + bv, 0.f);
        out[(size_t)orow * 128 + col] = (_Float16)v;
      }
    }
  }
}

// ---------------- aggregation: out[c] = relu(dc*(sum_e w_e t[src_e] + dc t[c]) + b) ----------------
__global__ __launch_bounds__(256) void agg_kernel(const _Float16* __restrict__ t,
                                                  const int* __restrict__ offs,
                                                  const int* __restrict__ csr_src,
                                                  const float* __restrict__ csr_w,
                                                  const float* __restrict__ dis,
                                                  const float* __restrict__ bias,
                                                  _Float16* __restrict__ out) {
  int c = blockIdx.x * 4 + (threadIdx.x >> 6);  // wave per node
  if (c >= NN) return;
  int lane = threadIdx.x & 63;
  float dc = dis[c];
  int s = offs[c], e = offs[c + 1];
  const f16x2* tc = (const f16x2*)t;
  f16x2 hv = tc[(size_t)c * 64 + lane];
  float ax = dc * (float)hv[0];
  float ay = dc * (float)hv[1];
  int k = s;
  for (; k + 4 <= e; k += 4) {
    int r0 = csr_src[k], r1 = csr_src[k + 1], r2 = csr_src[k + 2], r3 = csr_src[k + 3];
    float w0 = csr_w[k], w1 = csr_w[k + 1], w2 = csr_w[k + 2], w3 = csr_w[k + 3];
    f16x2 v0 = tc[(size_t)r0 * 64 + lane];
    f16x2 v1 = tc[(size_t)r1 * 64 + lane];
    f16x2 v2 = tc[(size_t)r2 * 64 + lane];
    f16x2 v3 = tc[(size_t)r3 * 64 + lane];
    ax += w0 * (float)v0[0] + w1 * (float)v1[0] + w2 * (float)v2[0] + w3 * (float)v3[0];
    ay += w0 * (float)v0[1] + w1 * (float)v1[1] + w2 * (float)v2[1] + w3 * (float)v3[1];
  }
  for (; k < e; ++k) {
    int r = csr_src[k];
    float w = csr_w[k];
    f16x2 v = tc[(size_t)r * 64 + lane];
    ax += w * (float)v[0];
    ay += w * (float)v[1];
  }
  f16x2 o;
  o[0] = (_Float16)fmaxf(ax * dc + bias[2 * lane], 0.f);
  o[1] = (_Float16)fmaxf(ay * dc + bias[2 * lane + 1], 0.f);
  ((f16x2*)out)[(size_t)c * 64 + lane] = o;
}

// ---------------- gate = ghidden . gW2 + gb2 ----------------
__global__ void gatedot_kernel(const _Float16* __restrict__ gh, const float* __restrict__ gW2,
                               const float* __restrict__ gb2, float* __restrict__ gate) {
  int row = blockIdx.x * 4 + (threadIdx.x >> 6);
  int lane = threadIdx.x & 63;
  if (row >= NN) return;
  const f16x2* r2 = (const f16x2*)gh + (size_t)row * 64;
  f16x2 v2 = r2[lane];
  float v = (float)v2[0] * gW2[2 * lane] + (float)v2[1] * gW2[2 * lane + 1];
#pragma unroll
  for (int o = 32; o > 0; o >>= 1) v += __shfl_down(v, o);
  if (lane == 0) gate[row] = v + gb2[0];
}

// ---------------- graph boundaries (batch sorted) ----------------
__global__ void bounds_kernel(const int* __restrict__ batch, int* gs, int* ge) {
  int i = blockIdx.x * 256 + threadIdx.x;
  if (i >= NN) return;
  int b = batch[i];
  if (i == 0 || batch[i - 1] != b) gs[b] = i;
  if (i == NN - 1 || batch[i + 1] != b) ge[b] = i + 1;
}

// ---------------- per-graph softmax + pool + MLP head ----------------
__global__ __launch_bounds__(256) void poolhead_kernel(
    const _Float16* __restrict__ h, const float* __restrict__ gate,
    const int* __restrict__ gs, const int* __restrict__ ge,
    const float* __restrict__ lW1, const float* __restrict__ lb1,
    const float* __restrict__ lW2, const float* __restrict__ lb2,
    float* __restrict__ out) {
  int g = blockIdx.x;
  int t = threadIdx.x;
  int s = gs[g], e = ge[g];
  __shared__ float red[4];
  __shared__ float pax[4][64], pay[4][64];
  __shared__ float pooled[128];
  __shared__ float hid[128];
  int wid = t >> 6, lane = t & 63;

  // max
  float m = -3.0e38f;
  for (int i = s + t; i < e; i += 256) m = fmaxf(m, gate[i]);
#pragma unroll
  for (int o = 32; o > 0; o >>= 1) m = fmaxf(m, __shfl_xor(m, o));
  if (lane == 0) red[wid] = m;
  __syncthreads();
  m = fmaxf(fmaxf(red[0], red[1]), fmaxf(red[2], red[3]));
  __syncthreads();

  // sum of exp
  float ds_ = 0.f;
  for (int i = s + t; i < e; i += 256) ds_ += __expf(gate[i] - m);
#pragma unroll
  for (int o = 32; o > 0; o >>= 1) ds_ += __shfl_xor(ds_, o);
  if (lane == 0) red[wid] = ds_;
  __syncthreads();
  float denom = red[0] + red[1] + red[2] + red[3];

  // weighted pool (fp16 h, f32 accumulate)
  const f16x2* h2 = (const f16x2*)h;
  int cp = t & 63, q = t >> 6;
  float px = 0.f, py = 0.f;
  for (int i = s + q; i < e; i += 4) {
    float w = __expf(gate[i] - m);
    f16x2 v = h2[(size_t)i * 64 + cp];
    px += w * (float)v[0];
    py += w * (float)v[1];
  }
  pax[q][cp] = px; pay[q][cp] = py;
  __syncthreads();
  if (t < 64) {
    float inv = (e > s) ? 1.f / denom : 0.f;
    float sx = pax[0][t] + pax[1][t] + pax[2][t] + pax[3][t];
    float sy = pay[0][t] + pay[1][t] + pay[2][t] + pay[3][t];
    pooled[2 * t] = sx * inv;
    pooled[2 * t + 1] = sy * inv;
  }
  __syncthreads();

  // head: hid = relu(pooled @ lW1 + lb1)
  if (t < 128) {
    float hv = lb1[t];
    for (int k = 0; k < 128; k++) hv += pooled[k] * lW1[k * 128 + t];
    hid[t] = fmaxf(hv, 0.f);
  }
  __syncthreads();

  // logits = hid @ lW2 + lb2
  if (t < OUTD) {
    float acc2 = lb2[t];
    for (int k = 0; k < 128; k++) acc2 += hid[k] * lW2[k * OUTD + t];
    out[g * OUTD + t] = acc2;
  }
}

extern "C" void kernel_launch(void* const* d_in, const int* in_sizes, int n_in,
                              void* d_out, int out_size, void* d_ws, size_t ws_size,
                              hipStream_t stream) {
  const float* x   = (const float*)d_in[0];
  const int*   ei  = (const int*)d_in[1];
  const int* batch = (const int*)d_in[2];
  const float* W0  = (const float*)d_in[3];
  const float* b0  = (const float*)d_in[4];
  const float* W1  = (const float*)d_in[5];
  const float* b1  = (const float*)d_in[6];
  const float* W2  = (const float*)d_in[7];
  const float* b2  = (const float*)d_in[8];
  const float* gW1 = (const float*)d_in[9];
  const float* gb1 = (const float*)d_in[10];
  const float* gW2 = (const float*)d_in[11];
  const float* gb2 = (const float*)d_in[12];
  const float* lW1 = (const float*)d_in[13];
  const float* lb1 = (const float*)d_in[14];
  const float* lW2 = (const float*)d_in[15];
  const float* lb2 = (const float*)d_in[16];
  float* out = (float*)d_out;

  char* w = (char*)d_ws;
  auto alloc = [&](size_t bytes) {
    char* p = w;
    w += (bytes + 255) & ~(size_t)255;
    return p;
  };
  _Float16* T  = (_Float16*)alloc((size_t)NN * 128 * 2);
  _Float16* HA = (_Float16*)alloc((size_t)NN * 128 * 2);
  _Float16* HB = (_Float16*)alloc((size_t)NN * 128 * 2);
  _Float16* Wt = (_Float16*)alloc((size_t)4 * 128 * 128 * 2);
  int* deg     = (int*)alloc((size_t)NN * 4);
  int* offs    = (int*)alloc((size_t)(NN + 1) * 4);
  int* cursor  = (int*)alloc((size_t)NN * 4);
  float* dis   = (float*)alloc((size_t)NN * 4);
  int* csr_src = (int*)alloc((size_t)EE * 4);
  float* csr_w = (float*)alloc((size_t)EE * 4);
  float* gate  = (float*)alloc((size_t)NN * 4);
  int* bsums   = (int*)alloc(64 * 4);
  int* gs      = (int*)alloc(GG * 4);
  int* ge      = (int*)alloc(GG * 4);

  dim3 b256(256);
  init_kernel<<<dim3((NN + 255) / 256), b256, 0, stream>>>(deg, gs, ge, out);
  prep_kernel<<<dim3(256), b256, 0, stream>>>(W0, W1, W2, gW1, Wt);
  count_kernel<<<dim3((EE + 255) / 256), b256, 0, stream>>>(ei, deg);
  scan1_kernel<<<dim3(49), b256, 0, stream>>>(deg, offs, bsums);
  scan2_kernel<<<dim3(1), dim3(64), 0, stream>>>(bsums, 49);
  scan3_kernel<<<dim3((NN + 255) / 256), b256, 0, stream>>>(deg, offs, cursor, dis, bsums);
  fill_kernel<<<dim3((EE + 255) / 256), b256, 0, stream>>>(ei, cursor, csr_src, csr_w, dis);

  int gblocks = (NN + 63) / 64;
  int ablocks = (NN + 3) / 4;
  // layer 0 (A = x in f32)
  gemm_kernel<1, 0><<<dim3(gblocks), b256, 0, stream>>>(x, Wt + 0 * 16384, nullptr, T, NN);
  agg_kernel<<<dim3(ablocks), b256, 0, stream>>>(T, offs, csr_src, csr_w, dis, b0, HA);
  // layer 1
  gemm_kernel<0, 0><<<dim3(gblocks), b256, 0, stream>>>(HA, Wt + 1 * 16384, nullptr, T, NN);
  agg_kernel<<<dim3(ablocks), b256, 0, stream>>>(T, offs, csr_src, csr_w, dis, b1, HB);
  // layer 2
  gemm_kernel<0, 0><<<dim3(gblocks), b256, 0, stream>>>(HB, Wt + 2 * 16384, nullptr, T, NN);
  agg_kernel<<<dim3(ablocks), b256, 0, stream>>>(T, offs, csr_src, csr_w, dis, b2, HA);

  // gate network
  gemm_kernel<0, 1><<<dim3(gblocks), b256, 0, stream>>>(HA, Wt + 3 * 16384, gb1, T, NN);
  gatedot_kernel<<<dim3(ablocks), b256, 0, stream>>>(T, gW2, gb2, gate);
  bounds_kernel<<<dim3((NN + 255) / 256), b256, 0, stream>>>(batch, gs, ge);
  poolhead_kernel<<<dim3(GG), b256, 0, stream>>>(HA, gate, gs, ge, lW1, lb1, lW2, lb2, out);
}

// Round 7
// 597.177 us; speedup vs baseline: 2.0903x; 1.0415x over previous
//
#include <hip/hip_runtime.h>
#include <math.h>

#define NN 100000
#define EE 1600000
#define HH 128
#define GG 512
#define OUTD 10

typedef _Float16 f16x2 __attribute__((ext_vector_type(2)));
typedef _Float16 f16x8 __attribute__((ext_vector_type(8)));
typedef float f32x4 __attribute__((ext_vector_type(4)));

// ---------------- init ----------------
__global__ void init_kernel(int* deg, int* gs, int* ge, float* out) {
  int i = blockIdx.x * 256 + threadIdx.x;
  if (i < NN) deg[i] = 1;            // self-loop
  if (i < GG) { gs[i] = 0; ge[i] = 0; }
  if (i == 0) out[GG * OUTD] = 0.0f; // the scalar second output
}

// ---------------- degree count ----------------
__global__ void count_kernel(const int* __restrict__ ei, int* __restrict__ deg) {
  int e = blockIdx.x * 256 + threadIdx.x;
  if (e >= EE) return;
  atomicAdd(&deg[ei[EE + e]], 1);    // col = ei[1][e]
}

// ---------------- exclusive scan of (deg-1), 2048 elems/block ----------------
__global__ __launch_bounds__(256) void scan1_kernel(const int* __restrict__ deg,
                                                    int* __restrict__ offs,
                                                    int* __restrict__ bsums) {
  __shared__ int ts[256];
  int t = threadIdx.x;
  int base = blockIdx.x * 2048 + t * 8;
  int v[8]; int s = 0;
#pragma unroll
  for (int i = 0; i < 8; i++) {
    int idx = base + i;
    int c = (idx < NN) ? (deg[idx] - 1) : 0;
    v[i] = s; s += c;
  }
  ts[t] = s;
  __syncthreads();
  for (int off = 1; off < 256; off <<= 1) {
    int x = (t >= off) ? ts[t - off] : 0;
    __syncthreads();
    ts[t] += x;
    __syncthreads();
  }
  int excl = (t == 0) ? 0 : ts[t - 1];
  if (t == 255) bsums[blockIdx.x] = ts[255];
#pragma unroll
  for (int i = 0; i < 8; i++) {
    int idx = base + i;
    if (idx < NN) offs[idx] = excl + v[i];
  }
}

__global__ void scan2_kernel(int* bsums, int nb) {
  if (threadIdx.x == 0 && blockIdx.x == 0) {
    int s = 0;
    for (int b = 0; b < nb; b++) { int x = bsums[b]; bsums[b] = s; s += x; }
  }
}

__global__ void scan3_kernel(const int* __restrict__ deg, int* __restrict__ offs,
                             int* __restrict__ cursor, float* __restrict__ dis,
                             const int* __restrict__ bsums) {
  int i = blockIdx.x * 256 + threadIdx.x;
  if (i >= NN) return;
  int o = offs[i] + bsums[i >> 11];
  offs[i] = o; cursor[i] = o;
  dis[i] = rsqrtf((float)deg[i]);    // deg >= 1 always
  if (i == NN - 1) offs[NN] = EE;
}

// ---------------- CSR fill (packed 8B entries: {src, weight bits}) ----------------
__global__ void fill_kernel(const int* __restrict__ ei, int* __restrict__ cursor,
                            int2* __restrict__ csr_p, const float* __restrict__ dis) {
  int e = blockIdx.x * 256 + threadIdx.x;
  if (e >= EE) return;
  int r = ei[e];
  int c = ei[EE + e];
  int slot = atomicAdd(&cursor[c], 1);
  csr_p[slot] = make_int2(r, __float_as_int(dis[r]));
}

// ---------------- weight transpose + fp16 convert: Wt[m][c][k] = W_m[k][c] ----------------
__global__ void prep_kernel(const float* __restrict__ W0, const float* __restrict__ W1,
                            const float* __restrict__ W2, const float* __restrict__ gW1,
                            _Float16* __restrict__ Wt) {
  int idx = blockIdx.x * 256 + threadIdx.x;   // 4*128*128 = 65536
  int m = idx >> 14;
  int rem = idx & 16383;
  int c = rem >> 7;
  int k = rem & 127;
  const float* src = (m == 0) ? W0 : (m == 1) ? W1 : (m == 2) ? W2 : gW1;
  Wt[idx] = (_Float16)src[k * 128 + c];
}

// ---------------- MFMA GEMM: [nrows,128] @ [128,128] ----------------
// Wt is the transposed fp16 weight [col][k]. AF32: A is f32 (layer 0), else fp16.
// MODE 0: plain fp16 store. MODE 2: fused gate epilogue (bias+relu, dot gW2, write gate; no store).
template <int AF32, int MODE>
__global__ __launch_bounds__(256) void gemm_kernel(const void* __restrict__ Av,
                                                   const _Float16* __restrict__ Wt,
                                                   const float* __restrict__ bias,
                                                   _Float16* __restrict__ out,
                                                   const float* __restrict__ gW2,
                                                   const float* __restrict__ gb2,
                                                   float* __restrict__ gate, int nrows) {
  __shared__ __align__(16) _Float16 wlds[128 * 136];  // padded stride 136 halves (272 B)
  int t = threadIdx.x;
  // stage Wt -> LDS (16B chunks; global chunk q == row q>>4, pos q&15)
  const uint4* src = (const uint4*)Wt;
#pragma unroll
  for (int i = 0; i < 8; i++) {
    int q = t + 256 * i;
    int c = q >> 4, p = q & 15;
    *(uint4*)&wlds[c * 136 + p * 8] = src[q];
  }
  __syncthreads();

  int wid = t >> 6, l = t & 63;
  int wr0 = blockIdx.x * 64 + wid * 16;
  int row = wr0 + (l & 15);
  bool valid = row < nrows;
  f16x8 zero8 = {(_Float16)0, (_Float16)0, (_Float16)0, (_Float16)0,
                 (_Float16)0, (_Float16)0, (_Float16)0, (_Float16)0};
  f16x8 af[4];
  if (AF32) {
    const float* ap = (const float*)Av + (size_t)row * 128;
#pragma unroll
    for (int kt = 0; kt < 4; kt++) {
      if (valid) {
        const float4* p4 = (const float4*)(ap + kt * 32 + (l >> 4) * 8);
        float4 u0 = p4[0], u1 = p4[1];
        f16x8 a;
        a[0] = (_Float16)u0.x; a[1] = (_Float16)u0.y; a[2] = (_Float16)u0.z; a[3] = (_Float16)u0.w;
        a[4] = (_Float16)u1.x; a[5] = (_Float16)u1.y; a[6] = (_Float16)u1.z; a[7] = (_Float16)u1.w;
        af[kt] = a;
      } else af[kt] = zero8;
    }
  } else {
    const _Float16* ap = (const _Float16*)Av + (size_t)row * 128;
#pragma unroll
    for (int kt = 0; kt < 4; kt++)
      af[kt] = valid ? *(const f16x8*)(ap + kt * 32 + (l >> 4) * 8) : zero8;
  }

  f32x4 acc[8] = {};
  int ko = (l >> 4) * 16;  // byte offset of this lane-group's k-chunk within a 64B kt block
#pragma unroll
  for (int n = 0; n < 8; n++) {
    int col = n * 16 + (l & 15);
    const char* base = (const char*)wlds + col * 272;
#pragma unroll
    for (int kt = 0; kt < 4; kt++) {
      f16x8 b = *(const f16x8*)(base + kt * 64 + ko);
      acc[n] = __builtin_amdgcn_mfma_f32_16x16x32_f16(af[kt], b, acc[n], 0, 0, 0);
    }
  }

  if (MODE == 0) {
#pragma unroll
    for (int n = 0; n < 8; n++) {
      int col = n * 16 + (l & 15);
#pragma unroll
      for (int r = 0; r < 4; r++) {
        int orow = wr0 + (l >> 4) * 4 + r;
        if (orow < nrows) out[(size_t)orow * 128 + col] = (_Float16)acc[n][r];
      }
    }
  } else {
    // fused gate: gate[row] = relu(acc+b) . gW2 + gb2
    float gp[4] = {0.f, 0.f, 0.f, 0.f};
    int c = l & 15;
#pragma unroll
    for (int n = 0; n < 8; n++) {
      int col = n * 16 + c;
      float bv = bias[col];
      float wv = gW2[col];
#pragma unroll
      for (int r = 0; r < 4; r++) gp[r] += fmaxf(acc[n][r] + bv, 0.f) * wv;
    }
#pragma unroll
    for (int m = 1; m < 16; m <<= 1) {
#pragma unroll
      for (int r = 0; r < 4; r++) gp[r] += __shfl_xor(gp[r], m);
    }
    if (c == 0) {
      float gb = gb2[0];
#pragma unroll
      for (int r = 0; r < 4; r++) {
        int orow = wr0 + (l >> 4) * 4 + r;
        if (orow < nrows) gate[orow] = gp[r] + gb;
      }
    }
  }
}

// ---------------- aggregation: out[c] = relu(dc*(sum_e w_e t[src_e] + dc t[c]) + b) ----------------
__global__ __launch_bounds__(256) void agg_kernel(const _Float16* __restrict__ t,
                                                  const int* __restrict__ offs,
                                                  const int2* __restrict__ csr_p,
                                                  const float* __restrict__ dis,
                                                  const float* __restrict__ bias,
                                                  _Float16* __restrict__ out) {
  int c = blockIdx.x * 4 + (threadIdx.x >> 6);  // wave per node
  if (c >= NN) return;
  int lane = threadIdx.x & 63;
  float dc = dis[c];
  int s = offs[c], e = offs[c + 1];
  const f16x2* tc = (const f16x2*)t;
  f16x2 hv = tc[(size_t)c * 64 + lane];
  float ax = dc * (float)hv[0];
  float ay = dc * (float)hv[1];
  int k = s;
  for (; k + 4 <= e; k += 4) {
    int2 p0 = csr_p[k], p1 = csr_p[k + 1], p2 = csr_p[k + 2], p3 = csr_p[k + 3];
    float w0 = __int_as_float(p0.y), w1 = __int_as_float(p1.y);
    float w2 = __int_as_float(p2.y), w3 = __int_as_float(p3.y);
    f16x2 v0 = tc[(size_t)p0.x * 64 + lane];
    f16x2 v1 = tc[(size_t)p1.x * 64 + lane];
    f16x2 v2 = tc[(size_t)p2.x * 64 + lane];
    f16x2 v3 = tc[(size_t)p3.x * 64 + lane];
    ax += w0 * (float)v0[0] + w1 * (float)v1[0] + w2 * (float)v2[0] + w3 * (float)v3[0];
    ay += w0 * (float)v0[1] + w1 * (float)v1[1] + w2 * (float)v2[1] + w3 * (float)v3[1];
  }
  for (; k < e; ++k) {
    int2 p = csr_p[k];
    float w = __int_as_float(p.y);
    f16x2 v = tc[(size_t)p.x * 64 + lane];
    ax += w * (float)v[0];
    ay += w * (float)v[1];
  }
  f16x2 o;
  o[0] = (_Float16)fmaxf(ax * dc + bias[2 * lane], 0.f);
  o[1] = (_Float16)fmaxf(ay * dc + bias[2 * lane + 1], 0.f);
  ((f16x2*)out)[(size_t)c * 64 + lane] = o;
}

// ---------------- graph boundaries (batch sorted) ----------------
__global__ void bounds_kernel(const int* __restrict__ batch, int* gs, int* ge) {
  int i = blockIdx.x * 256 + threadIdx.x;
  if (i >= NN) return;
  int b = batch[i];
  if (i == 0 || batch[i - 1] != b) gs[b] = i;
  if (i == NN - 1 || batch[i + 1] != b) ge[b] = i + 1;
}

// ---------------- per-graph softmax + pool + MLP head ----------------
__global__ __launch_bounds__(256) void poolhead_kernel(
    const _Float16* __restrict__ h, const float* __restrict__ gate,
    const int* __restrict__ gs, const int* __restrict__ ge,
    const float* __restrict__ lW1, const float* __restrict__ lb1,
    const float* __restrict__ lW2, const float* __restrict__ lb2,
    float* __restrict__ out) {
  int g = blockIdx.x;
  int t = threadIdx.x;
  int s = gs[g], e = ge[g];
  __shared__ float red[4];
  __shared__ float pax[4][64], pay[4][64];
  __shared__ float pooled[128];
  __shared__ float hid[128];
  int wid = t >> 6, lane = t & 63;

  // max
  float m = -3.0e38f;
  for (int i = s + t; i < e; i += 256) m = fmaxf(m, gate[i]);
#pragma unroll
  for (int o = 32; o > 0; o >>= 1) m = fmaxf(m, __shfl_xor(m, o));
  if (lane == 0) red[wid] = m;
  __syncthreads();
  m = fmaxf(fmaxf(red[0], red[1]), fmaxf(red[2], red[3]));
  __syncthreads();

  // sum of exp
  float ds_ = 0.f;
  for (int i = s + t; i < e; i += 256) ds_ += __expf(gate[i] - m);
#pragma unroll
  for (int o = 32; o > 0; o >>= 1) ds_ += __shfl_xor(ds_, o);
  if (lane == 0) red[wid] = ds_;
  __syncthreads();
  float denom = red[0] + red[1] + red[2] + red[3];

  // weighted pool (fp16 h, f32 accumulate)
  const f16x2* h2 = (const f16x2*)h;
  int cp = t & 63, q = t >> 6;
  float px = 0.f, py = 0.f;
  for (int i = s + q; i < e; i += 4) {
    float w = __expf(gate[i] - m);
    f16x2 v = h2[(size_t)i * 64 + cp];
    px += w * (float)v[0];
    py += w * (float)v[1];
  }
  pax[q][cp] = px; pay[q][cp] = py;
  __syncthreads();
  if (t < 64) {
    float inv = (e > s) ? 1.f / denom : 0.f;
    float sx = pax[0][t] + pax[1][t] + pax[2][t] + pax[3][t];
    float sy = pay[0][t] + pay[1][t] + pay[2][t] + pay[3][t];
    pooled[2 * t] = sx * inv;
    pooled[2 * t + 1] = sy * inv;
  }
  __syncthreads();

  // head: hid = relu(pooled @ lW1 + lb1)
  if (t < 128) {
    float hv = lb1[t];
    for (int k = 0; k < 128; k++) hv += pooled[k] * lW1[k * 128 + t];
    hid[t] = fmaxf(hv, 0.f);
  }
  __syncthreads();

  // logits = hid @ lW2 + lb2
  if (t < OUTD) {
    float acc2 = lb2[t];
    for (int k = 0; k < 128; k++) acc2 += hid[k] * lW2[k * OUTD + t];
    out[g * OUTD + t] = acc2;
  }
}

extern "C" void kernel_launch(void* const* d_in, const int* in_sizes, int n_in,
                              void* d_out, int out_size, void* d_ws, size_t ws_size,
                              hipStream_t stream) {
  const float* x   = (const float*)d_in[0];
  const int*   ei  = (const int*)d_in[1];
  const int* batch = (const int*)d_in[2];
  const float* W0  = (const float*)d_in[3];
  const float* b0  = (const float*)d_in[4];
  const float* W1  = (const float*)d_in[5];
  const float* b1  = (const float*)d_in[6];
  const float* W2  = (const float*)d_in[7];
  const float* b2  = (const float*)d_in[8];
  const float* gW1 = (const float*)d_in[9];
  const float* gb1 = (const float*)d_in[10];
  const float* gW2 = (const float*)d_in[11];
  const float* gb2 = (const float*)d_in[12];
  const float* lW1 = (const float*)d_in[13];
  const float* lb1 = (const float*)d_in[14];
  const float* lW2 = (const float*)d_in[15];
  const float* lb2 = (const float*)d_in[16];
  float* out = (float*)d_out;

  char* w = (char*)d_ws;
  auto alloc = [&](size_t bytes) {
    char* p = w;
    w += (bytes + 255) & ~(size_t)255;
    return p;
  };
  _Float16* T  = (_Float16*)alloc((size_t)NN * 128 * 2);
  _Float16* HA = (_Float16*)alloc((size_t)NN * 128 * 2);
  _Float16* HB = (_Float16*)alloc((size_t)NN * 128 * 2);
  _Float16* Wt = (_Float16*)alloc((size_t)4 * 128 * 128 * 2);
  int* deg     = (int*)alloc((size_t)NN * 4);
  int* offs    = (int*)alloc((size_t)(NN + 1) * 4);
  int* cursor  = (int*)alloc((size_t)NN * 4);
  float* dis   = (float*)alloc((size_t)NN * 4);
  int2* csr_p  = (int2*)alloc((size_t)EE * 8);
  float* gate  = (float*)alloc((size_t)NN * 4);
  int* bsums   = (int*)alloc(64 * 4);
  int* gs      = (int*)alloc(GG * 4);
  int* ge      = (int*)alloc(GG * 4);

  dim3 b256(256);
  init_kernel<<<dim3((NN + 255) / 256), b256, 0, stream>>>(deg, gs, ge, out);
  prep_kernel<<<dim3(256), b256, 0, stream>>>(W0, W1, W2, gW1, Wt);
  count_kernel<<<dim3((EE + 255) / 256), b256, 0, stream>>>(ei, deg);
  scan1_kernel<<<dim3(49), b256, 0, stream>>>(deg, offs, bsums);
  scan2_kernel<<<dim3(1), dim3(64), 0, stream>>>(bsums, 49);
  scan3_kernel<<<dim3((NN + 255) / 256), b256, 0, stream>>>(deg, offs, cursor, dis, bsums);
  fill_kernel<<<dim3((EE + 255) / 256), b256, 0, stream>>>(ei, cursor, csr_p, dis);

  int gblocks = (NN + 63) / 64;
  int ablocks = (NN + 3) / 4;
  // layer 0 (A = x in f32)
  gemm_kernel<1, 0><<<dim3(gblocks), b256, 0, stream>>>(x, Wt + 0 * 16384, nullptr, T, nullptr, nullptr, nullptr, NN);
  agg_kernel<<<dim3(ablocks), b256, 0, stream>>>(T, offs, csr_p, dis, b0, HA);
  // layer 1
  gemm_kernel<0, 0><<<dim3(gblocks), b256, 0, stream>>>(HA, Wt + 1 * 16384, nullptr, T, nullptr, nullptr, nullptr, NN);
  agg_kernel<<<dim3(ablocks), b256, 0, stream>>>(T, offs, csr_p, dis, b1, HB);
  // layer 2
  gemm_kernel<0, 0><<<dim3(gblocks), b256, 0, stream>>>(HB, Wt + 2 * 16384, nullptr, T, nullptr, nullptr, nullptr, NN);
  agg_kernel<<<dim3(ablocks), b256, 0, stream>>>(T, offs, csr_p, dis, b2, HA);

  // gate network: gate = relu(HA@gW1+gb1) . gW2 + gb2  (fused epilogue, no T store)
  gemm_kernel<0, 2><<<dim3(gblocks), b256, 0, stream>>>(HA, Wt + 3 * 16384, gb1, nullptr, gW2, gb2, gate, NN);
  bounds_kernel<<<dim3((NN + 255) / 256), b256, 0, stream>>>(batch, gs, ge);
  poolhead_kernel<<<dim3(GG), b256, 0, stream>>>(HA, gate, gs, ge, lW1, lb1, lW2, lb2, out);
}

// Round 9
// 583.520 us; speedup vs baseline: 2.1393x; 1.0234x over previous
//
#include <hip/hip_runtime.h>
#include <math.h>

#define NN 100000
#define EE 1600000
#define HH 128
#define GG 512
#define OUTD 10
#define NB 196   // buckets of 512 nodes: bucket = c >> 9
#define BSH 9

typedef _Float16 f16x2 __attribute__((ext_vector_type(2)));
typedef _Float16 f16x8 __attribute__((ext_vector_type(8)));
typedef float f32x4 __attribute__((ext_vector_type(4)));

// ---------------- init ----------------
__global__ void init_kernel(int* deg, int* gs, int* ge, int* bcount, float* out) {
  int i = blockIdx.x * 256 + threadIdx.x;
  if (i < NN) deg[i] = 1;            // self-loop
  if (i < GG) { gs[i] = 0; ge[i] = 0; }
  if (i < NB) bcount[i] = 0;
  if (i == 0) out[GG * OUTD] = 0.0f; // the scalar second output
}

// ---------------- pass A: bucket histogram + degree count ----------------
__global__ __launch_bounds__(256) void binA_kernel(const int* __restrict__ ei,
                                                   int* __restrict__ deg,
                                                   int* __restrict__ bcount) {
  __shared__ int lh[NB];
  for (int i = threadIdx.x; i < NB; i += 256) lh[i] = 0;
  __syncthreads();
  int e = blockIdx.x * 2048 + threadIdx.x;
#pragma unroll
  for (int i = 0; i < 8; i++, e += 256) {
    if (e < EE) {
      int c = ei[EE + e];
      atomicAdd(&deg[c], 1);
      atomicAdd(&lh[c >> BSH], 1);
    }
  }
  __syncthreads();
  for (int i = threadIdx.x; i < NB; i += 256)
    if (lh[i]) atomicAdd(&bcount[i], lh[i]);
}

// ---------------- bucket scan ----------------
__global__ __launch_bounds__(256) void bscan_kernel(const int* __restrict__ bcount,
                                                    int* __restrict__ boffs,
                                                    int* __restrict__ bcursor) {
  __shared__ int ts[256];
  int t = threadIdx.x;
  int v = (t < NB) ? bcount[t] : 0;
  ts[t] = v;
  __syncthreads();
  for (int off = 1; off < 256; off <<= 1) {
    int x = (t >= off) ? ts[t - off] : 0;
    __syncthreads();
    ts[t] += x;
    __syncthreads();
  }
  int excl = (t == 0) ? 0 : ts[t - 1];
  if (t < NB) { boffs[t] = excl; bcursor[t] = excl; }
  if (t == NB - 1) boffs[NB] = excl + v;
}

// ---------------- node-level exclusive scan of (deg-1), 2048 elems/block ----------------
__global__ __launch_bounds__(256) void scan1_kernel(const int* __restrict__ deg,
                                                    int* __restrict__ offs,
                                                    int* __restrict__ bsums) {
  __shared__ int ts[256];
  int t = threadIdx.x;
  int base = blockIdx.x * 2048 + t * 8;
  int v[8]; int s = 0;
#pragma unroll
  for (int i = 0; i < 8; i++) {
    int idx = base + i;
    int c = (idx < NN) ? (deg[idx] - 1) : 0;
    v[i] = s; s += c;
  }
  ts[t] = s;
  __syncthreads();
  for (int off = 1; off < 256; off <<= 1) {
    int x = (t >= off) ? ts[t - off] : 0;
    __syncthreads();
    ts[t] += x;
    __syncthreads();
  }
  int excl = (t == 0) ? 0 : ts[t - 1];
  if (t == 255) bsums[blockIdx.x] = ts[255];
#pragma unroll
  for (int i = 0; i < 8; i++) {
    int idx = base + i;
    if (idx < NN) offs[idx] = excl + v[i];
  }
}

__global__ void scan2_kernel(int* bsums, int nb) {
  if (threadIdx.x == 0 && blockIdx.x == 0) {
    int s = 0;
    for (int b = 0; b < nb; b++) { int x = bsums[b]; bsums[b] = s; s += x; }
  }
}

__global__ void scan3_kernel(const int* __restrict__ deg, int* __restrict__ offs,
                             int* __restrict__ cursor, float* __restrict__ dis,
                             const int* __restrict__ bsums) {
  int i = blockIdx.x * 256 + threadIdx.x;
  if (i >= NN) return;
  int o = offs[i] + bsums[i >> 11];
  offs[i] = o; cursor[i] = o;
  dis[i] = rsqrtf((float)deg[i]);    // deg >= 1 always
  if (i == NN - 1) offs[NN] = EE;
}

// ---------------- pass B: scatter {r,c} into bucket regions (L2-friendly) ----------------
__global__ __launch_bounds__(256) void binB_kernel(const int* __restrict__ ei,
                                                   int* __restrict__ bcursor,
                                                   int2* __restrict__ ebuf) {
  __shared__ int lh[NB];
  __shared__ int lbase[NB];
  for (int i = threadIdx.x; i < NB; i += 256) lh[i] = 0;
  __syncthreads();
  int e0 = blockIdx.x * 2048 + threadIdx.x;
  int r_[8], c_[8], rank_[8];
  int e = e0;
#pragma unroll
  for (int i = 0; i < 8; i++, e += 256) {
    if (e < EE) {
      r_[i] = ei[e];
      c_[i] = ei[EE + e];
      rank_[i] = atomicAdd(&lh[c_[i] >> BSH], 1);
    }
  }
  __syncthreads();
  for (int i = threadIdx.x; i < NB; i += 256)
    lbase[i] = lh[i] ? atomicAdd(&bcursor[i], lh[i]) : 0;
  __syncthreads();
  e = e0;
#pragma unroll
  for (int i = 0; i < 8; i++, e += 256) {
    if (e < EE) {
      int b = c_[i] >> BSH;
      ebuf[lbase[b] + rank_[i]] = make_int2(r_[i], c_[i]);
    }
  }
}

// ---------------- pass C: within-bucket fine scatter into csr_p ----------------
__global__ __launch_bounds__(256) void binC_kernel(const int2* __restrict__ ebuf,
                                                   const int* __restrict__ boffs,
                                                   int* __restrict__ cursor,
                                                   const float* __restrict__ dis,
                                                   int2* __restrict__ csr_p) {
  int b = blockIdx.x >> 3;
  int slice = blockIdx.x & 7;
  int s = boffs[b], e = boffs[b + 1];
  for (int i = s + slice * 256 + threadIdx.x; i < e; i += 2048) {
    int2 rc = ebuf[i];
    int slot = atomicAdd(&cursor[rc.y], 1);
    csr_p[slot] = make_int2(rc.x, __float_as_int(dis[rc.x]));
  }
}

// ---------------- weight transpose + fp16 convert: Wt[m][c][k] = W_m[k][c] ----------------
__global__ void prep_kernel(const float* __restrict__ W0, const float* __restrict__ W1,
                            const float* __restrict__ W2, const float* __restrict__ gW1,
                            _Float16* __restrict__ Wt) {
  int idx = blockIdx.x * 256 + threadIdx.x;   // 4*128*128 = 65536
  int m = idx >> 14;
  int rem = idx & 16383;
  int c = rem >> 7;
  int k = rem & 127;
  const float* src = (m == 0) ? W0 : (m == 1) ? W1 : (m == 2) ? W2 : gW1;
  Wt[idx] = (_Float16)src[k * 128 + c];
}

// ---------------- MFMA GEMM: [nrows,128] @ [128,128] ----------------
// Wt is the transposed fp16 weight [col][k]. AF32: A is f32 (layer 0), else fp16.
// MODE 0: plain fp16 store. MODE 2: fused gate epilogue (bias+relu, dot gW2, write gate; no store).
template <int AF32, int MODE>
__global__ __launch_bounds__(256) void gemm_kernel(const void* __restrict__ Av,
                                                   const _Float16* __restrict__ Wt,
                                                   const float* __restrict__ bias,
                                                   _Float16* __restrict__ out,
                                                   const float* __restrict__ gW2,
                                                   const float* __restrict__ gb2,
                                                   float* __restrict__ gate, int nrows) {
  __shared__ __align__(16) _Float16 wlds[128 * 136];  // padded stride 136 halves (272 B)
  int t = threadIdx.x;
  const uint4* src = (const uint4*)Wt;
#pragma unroll
  for (int i = 0; i < 8; i++) {
    int q = t + 256 * i;
    int c = q >> 4, p = q & 15;
    *(uint4*)&wlds[c * 136 + p * 8] = src[q];
  }
  __syncthreads();

  int wid = t >> 6, l = t & 63;
  int wr0 = blockIdx.x * 64 + wid * 16;
  int row = wr0 + (l & 15);
  bool valid = row < nrows;
  f16x8 zero8 = {(_Float16)0, (_Float16)0, (_Float16)0, (_Float16)0,
                 (_Float16)0, (_Float16)0, (_Float16)0, (_Float16)0};
  f16x8 af[4];
  if (AF32) {
    const float* ap = (const float*)Av + (size_t)row * 128;
#pragma unroll
    for (int kt = 0; kt < 4; kt++) {
      if (valid) {
        const float4* p4 = (const float4*)(ap + kt * 32 + (l >> 4) * 8);
        float4 u0 = p4[0], u1 = p4[1];
        f16x8 a;
        a[0] = (_Float16)u0.x; a[1] = (_Float16)u0.y; a[2] = (_Float16)u0.z; a[3] = (_Float16)u0.w;
        a[4] = (_Float16)u1.x; a[5] = (_Float16)u1.y; a[6] = (_Float16)u1.z; a[7] = (_Float16)u1.w;
        af[kt] = a;
      } else af[kt] = zero8;
    }
  } else {
    const _Float16* ap = (const _Float16*)Av + (size_t)row * 128;
#pragma unroll
    for (int kt = 0; kt < 4; kt++)
      af[kt] = valid ? *(const f16x8*)(ap + kt * 32 + (l >> 4) * 8) : zero8;
  }

  f32x4 acc[8] = {};
  int ko = (l >> 4) * 16;
#pragma unroll
  for (int n = 0; n < 8; n++) {
    int col = n * 16 + (l & 15);
    const char* base = (const char*)wlds + col * 272;
#pragma unroll
    for (int kt = 0; kt < 4; kt++) {
      f16x8 b = *(const f16x8*)(base + kt * 64 + ko);
      acc[n] = __builtin_amdgcn_mfma_f32_16x16x32_f16(af[kt], b, acc[n], 0, 0, 0);
    }
  }

  if (MODE == 0) {
#pragma unroll
    for (int n = 0; n < 8; n++) {
      int col = n * 16 + (l & 15);
#pragma unroll
      for (int r = 0; r < 4; r++) {
        int orow = wr0 + (l >> 4) * 4 + r;
        if (orow < nrows) out[(size_t)orow * 128 + col] = (_Float16)acc[n][r];
      }
    }
  } else {
    float gp[4] = {0.f, 0.f, 0.f, 0.f};
    int c = l & 15;
#pragma unroll
    for (int n = 0; n < 8; n++) {
      int col = n * 16 + c;
      float bv = bias[col];
      float wv = gW2[col];
#pragma unroll
      for (int r = 0; r < 4; r++) gp[r] += fmaxf(acc[n][r] + bv, 0.f) * wv;
    }
#pragma unroll
    for (int m = 1; m < 16; m <<= 1) {
#pragma unroll
      for (int r = 0; r < 4; r++) gp[r] += __shfl_xor(gp[r], m);
    }
    if (c == 0) {
      float gb = gb2[0];
#pragma unroll
      for (int r = 0; r < 4; r++) {
        int orow = wr0 + (l >> 4) * 4 + r;
        if (orow < nrows) gate[orow] = gp[r] + gb;
      }
    }
  }
}

// ---------------- aggregation: out[c] = relu(dc*(sum_e w_e t[src_e] + dc t[c]) + b) ----------------
__global__ __launch_bounds__(256) void agg_kernel(const _Float16* __restrict__ t,
                                                  const int* __restrict__ offs,
                                                  const int2* __restrict__ csr_p,
                                                  const float* __restrict__ dis,
                                                  const float* __restrict__ bias,
                                                  _Float16* __restrict__ out) {
  int c = blockIdx.x * 4 + (threadIdx.x >> 6);  // wave per node
  if (c >= NN) return;
  int lane = threadIdx.x & 63;
  float dc = dis[c];
  int s = offs[c], e = offs[c + 1];
  const f16x2* tc = (const f16x2*)t;
  f16x2 hv = tc[(size_t)c * 64 + lane];
  float ax = dc * (float)hv[0];
  float ay = dc * (float)hv[1];
  int k = s;
  for (; k + 4 <= e; k += 4) {
    int2 p0 = csr_p[k], p1 = csr_p[k + 1], p2 = csr_p[k + 2], p3 = csr_p[k + 3];
    float w0 = __int_as_float(p0.y), w1 = __int_as_float(p1.y);
    float w2 = __int_as_float(p2.y), w3 = __int_as_float(p3.y);
    f16x2 v0 = tc[(size_t)p0.x * 64 + lane];
    f16x2 v1 = tc[(size_t)p1.x * 64 + lane];
    f16x2 v2 = tc[(size_t)p2.x * 64 + lane];
    f16x2 v3 = tc[(size_t)p3.x * 64 + lane];
    ax += w0 * (float)v0[0] + w1 * (float)v1[0] + w2 * (float)v2[0] + w3 * (float)v3[0];
    ay += w0 * (float)v0[1] + w1 * (float)v1[1] + w2 * (float)v2[1] + w3 * (float)v3[1];
  }
  for (; k < e; ++k) {
    int2 p = csr_p[k];
    float w = __int_as_float(p.y);
    f16x2 v = tc[(size_t)p.x * 64 + lane];
    ax += w * (float)v[0];
    ay += w * (float)v[1];
  }
  f16x2 o;
  o[0] = (_Float16)fmaxf(ax * dc + bias[2 * lane], 0.f);
  o[1] = (_Float16)fmaxf(ay * dc + bias[2 * lane + 1], 0.f);
  ((f16x2*)out)[(size_t)c * 64 + lane] = o;
}

// ---------------- graph boundaries (batch sorted) ----------------
__global__ void bounds_kernel(const int* __restrict__ batch, int* gs, int* ge) {
  int i = blockIdx.x * 256 + threadIdx.x;
  if (i >= NN) return;
  int b = batch[i];
  if (i == 0 || batch[i - 1] != b) gs[b] = i;
  if (i == NN - 1 || batch[i + 1] != b) ge[b] = i + 1;
}

// ---------------- per-graph softmax + pool + MLP head ----------------
__global__ __launch_bounds__(256) void poolhead_kernel(
    const _Float16* __restrict__ h, const float* __restrict__ gate,
    const int* __restrict__ gs, const int* __restrict__ ge,
    const float* __restrict__ lW1, const float* __restrict__ lb1,
    const float* __restrict__ lW2, const float* __restrict__ lb2,
    float* __restrict__ out) {
  int g = blockIdx.x;
  int t = threadIdx.x;
  int s = gs[g], e = ge[g];
  __shared__ float red[4];
  __shared__ float pax[4][64], pay[4][64];
  __shared__ float pooled[128];
  __shared__ float hid[128];
  int wid = t >> 6, lane = t & 63;

  float m = -3.0e38f;
  for (int i = s + t; i < e; i += 256) m = fmaxf(m, gate[i]);
#pragma unroll
  for (int o = 32; o > 0; o >>= 1) m = fmaxf(m, __shfl_xor(m, o));
  if (lane == 0) red[wid] = m;
  __syncthreads();
  m = fmaxf(fmaxf(red[0], red[1]), fmaxf(red[2], red[3]));
  __syncthreads();

  float ds_ = 0.f;
  for (int i = s + t; i < e; i += 256) ds_ += __expf(gate[i] - m);
#pragma unroll
  for (int o = 32; o > 0; o >>= 1) ds_ += __shfl_xor(ds_, o);
  if (lane == 0) red[wid] = ds_;
  __syncthreads();
  float denom = red[0] + red[1] + red[2] + red[3];

  const f16x2* h2 = (const f16x2*)h;
  int cp = t & 63, q = t >> 6;
  float px = 0.f, py = 0.f;
  for (int i = s + q; i < e; i += 4) {
    float w = __expf(gate[i] - m);
    f16x2 v = h2[(size_t)i * 64 + cp];
    px += w * (float)v[0];
    py += w * (float)v[1];
  }
  pax[q][cp] = px; pay[q][cp] = py;
  __syncthreads();
  if (t < 64) {
    float inv = (e > s) ? 1.f / denom : 0.f;
    float sx = pax[0][t] + pax[1][t] + pax[2][t] + pax[3][t];
    float sy = pay[0][t] + pay[1][t] + pay[2][t] + pay[3][t];
    pooled[2 * t] = sx * inv;
    pooled[2 * t + 1] = sy * inv;
  }
  __syncthreads();

  if (t < 128) {
    float hv = lb1[t];
    for (int k = 0; k < 128; k++) hv += pooled[k] * lW1[k * 128 + t];
    hid[t] = fmaxf(hv, 0.f);
  }
  __syncthreads();

  if (t < OUTD) {
    float acc2 = lb2[t];
    for (int k = 0; k < 128; k++) acc2 += hid[k] * lW2[k * OUTD + t];
    out[g * OUTD + t] = acc2;
  }
}

extern "C" void kernel_launch(void* const* d_in, const int* in_sizes, int n_in,
                              void* d_out, int out_size, void* d_ws, size_t ws_size,
                              hipStream_t stream) {
  const float* x   = (const float*)d_in[0];
  const int*   ei  = (const int*)d_in[1];
  const int* batch = (const int*)d_in[2];
  const float* W0  = (const float*)d_in[3];
  const float* b0  = (const float*)d_in[4];
  const float* W1  = (const float*)d_in[5];
  const float* b1  = (const float*)d_in[6];
  const float* W2  = (const float*)d_in[7];
  const float* b2  = (const float*)d_in[8];
  const float* gW1 = (const float*)d_in[9];
  const float* gb1 = (const float*)d_in[10];
  const float* gW2 = (const float*)d_in[11];
  const float* gb2 = (const float*)d_in[12];
  const float* lW1 = (const float*)d_in[13];
  const float* lb1 = (const float*)d_in[14];
  const float* lW2 = (const float*)d_in[15];
  const float* lb2 = (const float*)d_in[16];
  float* out = (float*)d_out;

  char* w = (char*)d_ws;
  auto alloc = [&](size_t bytes) {
    char* p = w;
    w += (bytes + 255) & ~(size_t)255;
    return p;
  };
  _Float16* T  = (_Float16*)alloc((size_t)NN * 128 * 2);
  _Float16* HA = (_Float16*)alloc((size_t)NN * 128 * 2);
  _Float16* HB = (_Float16*)alloc((size_t)NN * 128 * 2);
  _Float16* Wt = (_Float16*)alloc((size_t)4 * 128 * 128 * 2);
  int* deg     = (int*)alloc((size_t)NN * 4);
  int* offs    = (int*)alloc((size_t)(NN + 1) * 4);
  int* cursor  = (int*)alloc((size_t)NN * 4);
  float* dis   = (float*)alloc((size_t)NN * 4);
  int2* csr_p  = (int2*)alloc((size_t)EE * 8);
  int2* ebuf   = (int2*)alloc((size_t)EE * 8);
  float* gate  = (float*)alloc((size_t)NN * 4);
  int* bsums   = (int*)alloc(64 * 4);
  int* gs      = (int*)alloc(GG * 4);
  int* ge      = (int*)alloc(GG * 4);
  int* bcount  = (int*)alloc(NB * 4);
  int* boffs   = (int*)alloc((NB + 1) * 4);
  int* bcursor = (int*)alloc(NB * 4);

  dim3 b256(256);
  init_kernel<<<dim3((NN + 255) / 256), b256, 0, stream>>>(deg, gs, ge, bcount, out);
  prep_kernel<<<dim3(256), b256, 0, stream>>>(W0, W1, W2, gW1, Wt);
  binA_kernel<<<dim3((EE + 2047) / 2048), b256, 0, stream>>>(ei, deg, bcount);
  bscan_kernel<<<dim3(1), b256, 0, stream>>>(bcount, boffs, bcursor);
  scan1_kernel<<<dim3(49), b256, 0, stream>>>(deg, offs, bsums);
  scan2_kernel<<<dim3(1), dim3(64), 0, stream>>>(bsums, 49);
  scan3_kernel<<<dim3((NN + 255) / 256), b256, 0, stream>>>(deg, offs, cursor, dis, bsums);
  binB_kernel<<<dim3((EE + 2047) / 2048), b256, 0, stream>>>(ei, bcursor, ebuf);
  binC_kernel<<<dim3(NB * 8), b256, 0, stream>>>(ebuf, boffs, cursor, dis, csr_p);

  int gblocks = (NN + 63) / 64;
  int ablocks = (NN + 3) / 4;
  // layer 0 (A = x in f32)
  gemm_kernel<1, 0><<<dim3(gblocks), b256, 0, stream>>>(x, Wt + 0 * 16384, nullptr, T, nullptr, nullptr, nullptr, NN);
  agg_kernel<<<dim3(ablocks), b256, 0, stream>>>(T, offs, csr_p, dis, b0, HA);
  // layer 1
  gemm_kernel<0, 0><<<dim3(gblocks), b256, 0, stream>>>(HA, Wt + 1 * 16384, nullptr, T, nullptr, nullptr, nullptr, NN);
  agg_kernel<<<dim3(ablocks), b256, 0, stream>>>(T, offs, csr_p, dis, b1, HB);
  // layer 2
  gemm_kernel<0, 0><<<dim3(gblocks), b256, 0, stream>>>(HB, Wt + 2 * 16384, nullptr, T, nullptr, nullptr, nullptr, NN);
  agg_kernel<<<dim3(ablocks), b256, 0, stream>>>(T, offs, csr_p, dis, b2, HA);

  // gate network: gate = relu(HA@gW1+gb1) . gW2 + gb2  (fused epilogue, no T store)
  gemm_kernel<0, 2><<<dim3(gblocks), b256, 0, stream>>>(HA, Wt + 3 * 16384, gb1, nullptr, gW2, gb2, gate, NN);
  bounds_kernel<<<dim3((NN + 255) / 256), b256, 0, stream>>>(batch, gs, ge);
  poolhead_kernel<<<dim3(GG), b256, 0, stream>>>(HA, gate, gs, ge, lW1, lb1, lW2, lb2, out);
}

// Round 10
// 508.385 us; speedup vs baseline: 2.4554x; 1.1478x over previous
//
#include <hip/hip_runtime.h>
#include <math.h>

#define NN 100000
#define EE 1600000
#define HH 128
#define GG 512
#define OUTD 10
#define NB 196   // buckets of 512 nodes: bucket = c >> 9
#define BSH 9

typedef _Float16 f16x2 __attribute__((ext_vector_type(2)));
typedef _Float16 f16x8 __attribute__((ext_vector_type(8)));
typedef float f32x4 __attribute__((ext_vector_type(4)));

// ---------------- init ----------------
__global__ void init_kernel(int* gs, int* ge, int* bcount, float* out) {
  int i = blockIdx.x * 256 + threadIdx.x;
  if (i < GG) { gs[i] = 0; ge[i] = 0; }
  if (i < NB) bcount[i] = 0;
  if (i == 0) out[GG * OUTD] = 0.0f; // the scalar second output
}

// ---------------- pass A: bucket histogram (LDS only, no global atom" scatter) ----------------
__global__ __launch_bounds__(256) void binA_kernel(const int* __restrict__ ei,
                                                   int* __restrict__ bcount) {
  __shared__ int lh[NB];
  for (int i = threadIdx.x; i < NB; i += 256) lh[i] = 0;
  __syncthreads();
  int e = blockIdx.x * 2048 + threadIdx.x;
#pragma unroll
  for (int i = 0; i < 8; i++, e += 256)
    if (e < EE) atomicAdd(&lh[ei[EE + e] >> BSH], 1);
  __syncthreads();
  for (int i = threadIdx.x; i < NB; i += 256)
    if (lh[i]) atomicAdd(&bcount[i], lh[i]);
}

// ---------------- bucket scan ----------------
__global__ __launch_bounds__(256) void bscan_kernel(const int* __restrict__ bcount,
                                                    int* __restrict__ boffs,
                                                    int* __restrict__ bcursor) {
  __shared__ int ts[256];
  int t = threadIdx.x;
  int v = (t < NB) ? bcount[t] : 0;
  ts[t] = v;
  __syncthreads();
  for (int off = 1; off < 256; off <<= 1) {
    int x = (t >= off) ? ts[t - off] : 0;
    __syncthreads();
    ts[t] += x;
    __syncthreads();
  }
  int excl = (t == 0) ? 0 : ts[t - 1];
  if (t < NB) { boffs[t] = excl; bcursor[t] = excl; }
  if (t == NB - 1) boffs[NB] = excl + v;
}

// ---------------- pass B: scatter {r,c} into bucket regions (L2-friendly) ----------------
__global__ __launch_bounds__(256) void binB_kernel(const int* __restrict__ ei,
                                                   int* __restrict__ bcursor,
                                                   int2* __restrict__ ebuf) {
  __shared__ int lh[NB];
  __shared__ int lbase[NB];
  for (int i = threadIdx.x; i < NB; i += 256) lh[i] = 0;
  __syncthreads();
  int e0 = blockIdx.x * 2048 + threadIdx.x;
  int r_[8], c_[8], rank_[8];
  int e = e0;
#pragma unroll
  for (int i = 0; i < 8; i++, e += 256) {
    if (e < EE) {
      r_[i] = ei[e];
      c_[i] = ei[EE + e];
      rank_[i] = atomicAdd(&lh[c_[i] >> BSH], 1);
    }
  }
  __syncthreads();
  for (int i = threadIdx.x; i < NB; i += 256)
    lbase[i] = lh[i] ? atomicAdd(&bcursor[i], lh[i]) : 0;
  __syncthreads();
  e = e0;
#pragma unroll
  for (int i = 0; i < 8; i++, e += 256) {
    if (e < EE) {
      int b = c_[i] >> BSH;
      ebuf[lbase[b] + rank_[i]] = make_int2(r_[i], c_[i]);
    }
  }
}

// ---------------- pass D: per-bucket node degree via LDS counters ----------------
__global__ __launch_bounds__(256) void binD_kernel(const int2* __restrict__ ebuf,
                                                   const int* __restrict__ boffs,
                                                   int* __restrict__ deg) {
  __shared__ int lcnt[512];
  int b = blockIdx.x;
  for (int i = threadIdx.x; i < 512; i += 256) lcnt[i] = 0;
  __syncthreads();
  int s = boffs[b], e = boffs[b + 1];
  for (int i = s + threadIdx.x; i < e; i += 256)
    atomicAdd(&lcnt[ebuf[i].y & 511], 1);
  __syncthreads();
  int base = b << BSH;
  for (int i = threadIdx.x; i < 512; i += 256) {
    int node = base + i;
    if (node < NN) deg[node] = lcnt[i] + 1;   // +1 self-loop
  }
}

// ---------------- node-level exclusive scan of (deg-1), 2048 elems/block ----------------
__global__ __launch_bounds__(256) void scan1_kernel(const int* __restrict__ deg,
                                                    int* __restrict__ offs,
                                                    int* __restrict__ bsums) {
  __shared__ int ts[256];
  int t = threadIdx.x;
  int base = blockIdx.x * 2048 + t * 8;
  int v[8]; int s = 0;
#pragma unroll
  for (int i = 0; i < 8; i++) {
    int idx = base + i;
    int c = (idx < NN) ? (deg[idx] - 1) : 0;
    v[i] = s; s += c;
  }
  ts[t] = s;
  __syncthreads();
  for (int off = 1; off < 256; off <<= 1) {
    int x = (t >= off) ? ts[t - off] : 0;
    __syncthreads();
    ts[t] += x;
    __syncthreads();
  }
  int excl = (t == 0) ? 0 : ts[t - 1];
  if (t == 255) bsums[blockIdx.x] = ts[255];
#pragma unroll
  for (int i = 0; i < 8; i++) {
    int idx = base + i;
    if (idx < NN) offs[idx] = excl + v[i];
  }
}

__global__ void scan2_kernel(int* bsums, int nb) {
  if (threadIdx.x == 0 && blockIdx.x == 0) {
    int s = 0;
    for (int b = 0; b < nb; b++) { int x = bsums[b]; bsums[b] = s; s += x; }
  }
}

__global__ void scan3_kernel(const int* __restrict__ deg, int* __restrict__ offs,
                             float* __restrict__ dis, const int* __restrict__ bsums) {
  int i = blockIdx.x * 256 + threadIdx.x;
  if (i >= NN) return;
  int o = offs[i] + bsums[i >> 11];
  offs[i] = o;
  dis[i] = rsqrtf((float)deg[i]);    // deg >= 1 always
  if (i == NN - 1) offs[NN] = EE;
}

// ---------------- pass C: per-bucket fine scatter with LDS cursors ----------------
__global__ __launch_bounds__(256) void binC_kernel(const int2* __restrict__ ebuf,
                                                   const int* __restrict__ boffs,
                                                   const int* __restrict__ offs,
                                                   const float* __restrict__ dis,
                                                   int2* __restrict__ csr_p) {
  __shared__ int lcur[512];
  int b = blockIdx.x;
  int base = b << BSH;
  for (int i = threadIdx.x; i < 512; i += 256) {
    int node = base + i;
    lcur[i] = (node < NN) ? offs[node] : 0;
  }
  __syncthreads();
  int s = boffs[b], e = boffs[b + 1];
  for (int i = s + threadIdx.x; i < e; i += 256) {
    int2 rc = ebuf[i];
    int slot = atomicAdd(&lcur[rc.y & 511], 1);
    csr_p[slot] = make_int2(rc.x, __float_as_int(dis[rc.x]));
  }
}

// ---------------- weight transpose + fp16 convert: Wt[m][c][k] = W_m[k][c] ----------------
__global__ void prep_kernel(const float* __restrict__ W0, const float* __restrict__ W1,
                            const float* __restrict__ W2, const float* __restrict__ gW1,
                            _Float16* __restrict__ Wt) {
  int idx = blockIdx.x * 256 + threadIdx.x;   // 4*128*128 = 65536
  int m = idx >> 14;
  int rem = idx & 16383;
  int c = rem >> 7;
  int k = rem & 127;
  const float* src = (m == 0) ? W0 : (m == 1) ? W1 : (m == 2) ? W2 : gW1;
  Wt[idx] = (_Float16)src[k * 128 + c];
}

// ---------------- MFMA GEMM: [nrows,128] @ [128,128] ----------------
template <int AF32, int MODE>
__global__ __launch_bounds__(256) void gemm_kernel(const void* __restrict__ Av,
                                                   const _Float16* __restrict__ Wt,
                                                   const float* __restrict__ bias,
                                                   _Float16* __restrict__ out,
                                                   const float* __restrict__ gW2,
                                                   const float* __restrict__ gb2,
                                                   float* __restrict__ gate, int nrows) {
  __shared__ __align__(16) _Float16 wlds[128 * 136];  // padded stride 136 halves (272 B)
  int t = threadIdx.x;
  const uint4* src = (const uint4*)Wt;
#pragma unroll
  for (int i = 0; i < 8; i++) {
    int q = t + 256 * i;
    int c = q >> 4, p = q & 15;
    *(uint4*)&wlds[c * 136 + p * 8] = src[q];
  }
  __syncthreads();

  int wid = t >> 6, l = t & 63;
  int wr0 = blockIdx.x * 64 + wid * 16;
  int row = wr0 + (l & 15);
  bool valid = row < nrows;
  f16x8 zero8 = {(_Float16)0, (_Float16)0, (_Float16)0, (_Float16)0,
                 (_Float16)0, (_Float16)0, (_Float16)0, (_Float16)0};
  f16x8 af[4];
  if (AF32) {
    const float* ap = (const float*)Av + (size_t)row * 128;
#pragma unroll
    for (int kt = 0; kt < 4; kt++) {
      if (valid) {
        const float4* p4 = (const float4*)(ap + kt * 32 + (l >> 4) * 8);
        float4 u0 = p4[0], u1 = p4[1];
        f16x8 a;
        a[0] = (_Float16)u0.x; a[1] = (_Float16)u0.y; a[2] = (_Float16)u0.z; a[3] = (_Float16)u0.w;
        a[4] = (_Float16)u1.x; a[5] = (_Float16)u1.y; a[6] = (_Float16)u1.z; a[7] = (_Float16)u1.w;
        af[kt] = a;
      } else af[kt] = zero8;
    }
  } else {
    const _Float16* ap = (const _Float16*)Av + (size_t)row * 128;
#pragma unroll
    for (int kt = 0; kt < 4; kt++)
      af[kt] = valid ? *(const f16x8*)(ap + kt * 32 + (l >> 4) * 8) : zero8;
  }

  f32x4 acc[8] = {};
  int ko = (l >> 4) * 16;
#pragma unroll
  for (int n = 0; n < 8; n++) {
    int col = n * 16 + (l & 15);
    const char* base = (const char*)wlds + col * 272;
#pragma unroll
    for (int kt = 0; kt < 4; kt++) {
      f16x8 b = *(const f16x8*)(base + kt * 64 + ko);
      acc[n] = __builtin_amdgcn_mfma_f32_16x16x32_f16(af[kt], b, acc[n], 0, 0, 0);
    }
  }

  if (MODE == 0) {
#pragma unroll
    for (int n = 0; n < 8; n++) {
      int col = n * 16 + (l & 15);
#pragma unroll
      for (int r = 0; r < 4; r++) {
        int orow = wr0 + (l >> 4) * 4 + r;
        if (orow < nrows) out[(size_t)orow * 128 + col] = (_Float16)acc[n][r];
      }
    }
  } else {
    float gp[4] = {0.f, 0.f, 0.f, 0.f};
    int c = l & 15;
#pragma unroll
    for (int n = 0; n < 8; n++) {
      int col = n * 16 + c;
      float bv = bias[col];
      float wv = gW2[col];
#pragma unroll
      for (int r = 0; r < 4; r++) gp[r] += fmaxf(acc[n][r] + bv, 0.f) * wv;
    }
#pragma unroll
    for (int m = 1; m < 16; m <<= 1) {
#pragma unroll
      for (int r = 0; r < 4; r++) gp[r] += __shfl_xor(gp[r], m);
    }
    if (c == 0) {
      float gb = gb2[0];
#pragma unroll
      for (int r = 0; r < 4; r++) {
        int orow = wr0 + (l >> 4) * 4 + r;
        if (orow < nrows) gate[orow] = gp[r] + gb;
      }
    }
  }
}

// ---------------- aggregation: out[c] = relu(dc*(sum_e w_e t[src_e] + dc t[c]) + b) ----------------
__global__ __launch_bounds__(256) void agg_kernel(const _Float16* __restrict__ t,
                                                  const int* __restrict__ offs,
                                                  const int2* __restrict__ csr_p,
                                                  const float* __restrict__ dis,
                                                  const float* __restrict__ bias,
                                                  _Float16* __restrict__ out) {
  int c = blockIdx.x * 4 + (threadIdx.x >> 6);  // wave per node
  if (c >= NN) return;
  int lane = threadIdx.x & 63;
  float dc = dis[c];
  int s = offs[c], e = offs[c + 1];
  const f16x2* tc = (const f16x2*)t;
  f16x2 hv = tc[(size_t)c * 64 + lane];
  float ax = dc * (float)hv[0];
  float ay = dc * (float)hv[1];
  int k = s;
  for (; k + 4 <= e; k += 4) {
    int2 p0 = csr_p[k], p1 = csr_p[k + 1], p2 = csr_p[k + 2], p3 = csr_p[k + 3];
    float w0 = __int_as_float(p0.y), w1 = __int_as_float(p1.y);
    float w2 = __int_as_float(p2.y), w3 = __int_as_float(p3.y);
    f16x2 v0 = tc[(size_t)p0.x * 64 + lane];
    f16x2 v1 = tc[(size_t)p1.x * 64 + lane];
    f16x2 v2 = tc[(size_t)p2.x * 64 + lane];
    f16x2 v3 = tc[(size_t)p3.x * 64 + lane];
    ax += w0 * (float)v0[0] + w1 * (float)v1[0] + w2 * (float)v2[0] + w3 * (float)v3[0];
    ay += w0 * (float)v0[1] + w1 * (float)v1[1] + w2 * (float)v2[1] + w3 * (float)v3[1];
  }
  for (; k < e; ++k) {
    int2 p = csr_p[k];
    float w = __int_as_float(p.y);
    f16x2 v = tc[(size_t)p.x * 64 + lane];
    ax += w * (float)v[0];
    ay += w * (float)v[1];
  }
  f16x2 o;
  o[0] = (_Float16)fmaxf(ax * dc + bias[2 * lane], 0.f);
  o[1] = (_Float16)fmaxf(ay * dc + bias[2 * lane + 1], 0.f);
  ((f16x2*)out)[(size_t)c * 64 + lane] = o;
}

// ---------------- graph boundaries (batch sorted) ----------------
__global__ void bounds_kernel(const int* __restrict__ batch, int* gs, int* ge) {
  int i = blockIdx.x * 256 + threadIdx.x;
  if (i >= NN) return;
  int b = batch[i];
  if (i == 0 || batch[i - 1] != b) gs[b] = i;
  if (i == NN - 1 || batch[i + 1] != b) ge[b] = i + 1;
}

// ---------------- per-graph softmax + pool + MLP head ----------------
__global__ __launch_bounds__(256) void poolhead_kernel(
    const _Float16* __restrict__ h, const float* __restrict__ gate,
    const int* __restrict__ gs, const int* __restrict__ ge,
    const float* __restrict__ lW1, const float* __restrict__ lb1,
    const float* __restrict__ lW2, const float* __restrict__ lb2,
    float* __restrict__ out) {
  int g = blockIdx.x;
  int t = threadIdx.x;
  int s = gs[g], e = ge[g];
  __shared__ float red[4];
  __shared__ float pax[4][64], pay[4][64];
  __shared__ float pooled[128];
  __shared__ float hid[128];
  int wid = t >> 6, lane = t & 63;

  float m = -3.0e38f;
  for (int i = s + t; i < e; i += 256) m = fmaxf(m, gate[i]);
#pragma unroll
  for (int o = 32; o > 0; o >>= 1) m = fmaxf(m, __shfl_xor(m, o));
  if (lane == 0) red[wid] = m;
  __syncthreads();
  m = fmaxf(fmaxf(red[0], red[1]), fmaxf(red[2], red[3]));
  __syncthreads();

  float ds_ = 0.f;
  for (int i = s + t; i < e; i += 256) ds_ += __expf(gate[i] - m);
#pragma unroll
  for (int o = 32; o > 0; o >>= 1) ds_ += __shfl_xor(ds_, o);
  if (lane == 0) red[wid] = ds_;
  __syncthreads();
  float denom = red[0] + red[1] + red[2] + red[3];

  const f16x2* h2 = (const f16x2*)h;
  int cp = t & 63, q = t >> 6;
  float px = 0.f, py = 0.f;
  for (int i = s + q; i < e; i += 4) {
    float w = __expf(gate[i] - m);
    f16x2 v = h2[(size_t)i * 64 + cp];
    px += w * (float)v[0];
    py += w * (float)v[1];
  }
  pax[q][cp] = px; pay[q][cp] = py;
  __syncthreads();
  if (t < 64) {
    float inv = (e > s) ? 1.f / denom : 0.f;
    float sx = pax[0][t] + pax[1][t] + pax[2][t] + pax[3][t];
    float sy = pay[0][t] + pay[1][t] + pay[2][t] + pay[3][t];
    pooled[2 * t] = sx * inv;
    pooled[2 * t + 1] = sy * inv;
  }
  __syncthreads();

  if (t < 128) {
    float hv = lb1[t];
    for (int k = 0; k < 128; k++) hv += pooled[k] * lW1[k * 128 + t];
    hid[t] = fmaxf(hv, 0.f);
  }
  __syncthreads();

  if (t < OUTD) {
    float acc2 = lb2[t];
    for (int k = 0; k < 128; k++) acc2 += hid[k] * lW2[k * OUTD + t];
    out[g * OUTD + t] = acc2;
  }
}

extern "C" void kernel_launch(void* const* d_in, const int* in_sizes, int n_in,
                              void* d_out, int out_size, void* d_ws, size_t ws_size,
                              hipStream_t stream) {
  const float* x   = (const float*)d_in[0];
  const int*   ei  = (const int*)d_in[1];
  const int* batch = (const int*)d_in[2];
  const float* W0  = (const float*)d_in[3];
  const float* b0  = (const float*)d_in[4];
  const float* W1  = (const float*)d_in[5];
  const float* b1  = (const float*)d_in[6];
  const float* W2  = (const float*)d_in[7];
  const float* b2  = (const float*)d_in[8];
  const float* gW1 = (const float*)d_in[9];
  const float* gb1 = (const float*)d_in[10];
  const float* gW2 = (const float*)d_in[11];
  const float* gb2 = (const float*)d_in[12];
  const float* lW1 = (const float*)d_in[13];
  const float* lb1 = (const float*)d_in[14];
  const float* lW2 = (const float*)d_in[15];
  const float* lb2 = (const float*)d_in[16];
  float* out = (float*)d_out;

  char* w = (char*)d_ws;
  auto alloc = [&](size_t bytes) {
    char* p = w;
    w += (bytes + 255) & ~(size_t)255;
    return p;
  };
  _Float16* T  = (_Float16*)alloc((size_t)NN * 128 * 2);
  _Float16* HA = (_Float16*)alloc((size_t)NN * 128 * 2);
  _Float16* HB = (_Float16*)alloc((size_t)NN * 128 * 2);
  _Float16* Wt = (_Float16*)alloc((size_t)4 * 128 * 128 * 2);
  int* deg     = (int*)alloc((size_t)NN * 4);
  int* offs    = (int*)alloc((size_t)(NN + 1) * 4);
  float* dis   = (float*)alloc((size_t)NN * 4);
  int2* csr_p  = (int2*)alloc((size_t)EE * 8);
  int2* ebuf   = (int2*)alloc((size_t)EE * 8);
  float* gate  = (float*)alloc((size_t)NN * 4);
  int* bsums   = (int*)alloc(64 * 4);
  int* gs      = (int*)alloc(GG * 4);
  int* ge      = (int*)alloc(GG * 4);
  int* bcount  = (int*)alloc(NB * 4);
  int* boffs   = (int*)alloc((NB + 1) * 4);
  int* bcursor = (int*)alloc(NB * 4);

  dim3 b256(256);
  init_kernel<<<dim3(2), b256, 0, stream>>>(gs, ge, bcount, out);
  prep_kernel<<<dim3(256), b256, 0, stream>>>(W0, W1, W2, gW1, Wt);
  binA_kernel<<<dim3((EE + 2047) / 2048), b256, 0, stream>>>(ei, bcount);
  bscan_kernel<<<dim3(1), b256, 0, stream>>>(bcount, boffs, bcursor);
  binB_kernel<<<dim3((EE + 2047) / 2048), b256, 0, stream>>>(ei, bcursor, ebuf);
  binD_kernel<<<dim3(NB), b256, 0, stream>>>(ebuf, boffs, deg);
  scan1_kernel<<<dim3(49), b256, 0, stream>>>(deg, offs, bsums);
  scan2_kernel<<<dim3(1), dim3(64), 0, stream>>>(bsums, 49);
  scan3_kernel<<<dim3((NN + 255) / 256), b256, 0, stream>>>(deg, offs, dis, bsums);
  binC_kernel<<<dim3(NB), b256, 0, stream>>>(ebuf, boffs, offs, dis, csr_p);

  int gblocks = (NN + 63) / 64;
  int ablocks = (NN + 3) / 4;
  // layer 0 (A = x in f32)
  gemm_kernel<1, 0><<<dim3(gblocks), b256, 0, stream>>>(x, Wt + 0 * 16384, nullptr, T, nullptr, nullptr, nullptr, NN);
  agg_kernel<<<dim3(ablocks), b256, 0, stream>>>(T, offs, csr_p, dis, b0, HA);
  // layer 1
  gemm_kernel<0, 0><<<dim3(gblocks), b256, 0, stream>>>(HA, Wt + 1 * 16384, nullptr, T, nullptr, nullptr, nullptr, NN);
  agg_kernel<<<dim3(ablocks), b256, 0, stream>>>(T, offs, csr_p, dis, b1, HB);
  // layer 2
  gemm_kernel<0, 0><<<dim3(gblocks), b256, 0, stream>>>(HB, Wt + 2 * 16384, nullptr, T, nullptr, nullptr, nullptr, NN);
  agg_kernel<<<dim3(ablocks), b256, 0, stream>>>(T, offs, csr_p, dis, b2, HA);

  // gate network: gate = relu(HA@gW1+gb1) . gW2 + gb2  (fused epilogue, no T store)
  gemm_kernel<0, 2><<<dim3(gblocks), b256, 0, stream>>>(HA, Wt + 3 * 16384, gb1, nullptr, gW2, gb2, gate, NN);
  bounds_kernel<<<dim3((NN + 255) / 256), b256, 0, stream>>>(batch, gs, ge);
  poolhead_kernel<<<dim3(GG), b256, 0, stream>>>(HA, gate, gs, ge, lW1, lb1, lW2, lb2, out);
}

// Round 11
// 474.721 us; speedup vs baseline: 2.6296x; 1.0709x over previous
//
#include <hip/hip_runtime.h>
#include <math.h>

#define NN 100000
#define EE 1600000
#define HH 128
#define GG 512
#define OUTD 10
#define NB 196   // buckets of 512 nodes: bucket = c >> 9
#define BSH 9

typedef _Float16 f16x2 __attribute__((ext_vector_type(2)));
typedef _Float16 f16x4 __attribute__((ext_vector_type(4)));
typedef _Float16 f16x8 __attribute__((ext_vector_type(8)));
typedef float f32x4 __attribute__((ext_vector_type(4)));

// ---------------- init ----------------
__global__ void init_kernel(int* gs, int* ge, int* bcount, float* out) {
  int i = blockIdx.x * 256 + threadIdx.x;
  if (i < GG) { gs[i] = 0; ge[i] = 0; }
  if (i < NB) bcount[i] = 0;
  if (i == 0) out[GG * OUTD] = 0.0f; // the scalar second output
}

// ---------------- pass A: bucket histogram (LDS only) ----------------
__global__ __launch_bounds__(256) void binA_kernel(const int* __restrict__ ei,
                                                   int* __restrict__ bcount) {
  __shared__ int lh[NB];
  for (int i = threadIdx.x; i < NB; i += 256) lh[i] = 0;
  __syncthreads();
  int e = blockIdx.x * 2048 + threadIdx.x;
#pragma unroll
  for (int i = 0; i < 8; i++, e += 256)
    if (e < EE) atomicAdd(&lh[ei[EE + e] >> BSH], 1);
  __syncthreads();
  for (int i = threadIdx.x; i < NB; i += 256)
    if (lh[i]) atomicAdd(&bcount[i], lh[i]);
}

// ---------------- bucket scan ----------------
__global__ __launch_bounds__(256) void bscan_kernel(const int* __restrict__ bcount,
                                                    int* __restrict__ boffs,
                                                    int* __restrict__ bcursor) {
  __shared__ int ts[256];
  int t = threadIdx.x;
  int v = (t < NB) ? bcount[t] : 0;
  ts[t] = v;
  __syncthreads();
  for (int off = 1; off < 256; off <<= 1) {
    int x = (t >= off) ? ts[t - off] : 0;
    __syncthreads();
    ts[t] += x;
    __syncthreads();
  }
  int excl = (t == 0) ? 0 : ts[t - 1];
  if (t < NB) { boffs[t] = excl; bcursor[t] = excl; }
  if (t == NB - 1) boffs[NB] = excl + v;
}

// ---------------- pass B: scatter {r,c} into bucket regions (L2-friendly) ----------------
__global__ __launch_bounds__(256) void binB_kernel(const int* __restrict__ ei,
                                                   int* __restrict__ bcursor,
                                                   int2* __restrict__ ebuf) {
  __shared__ int lh[NB];
  __shared__ int lbase[NB];
  for (int i = threadIdx.x; i < NB; i += 256) lh[i] = 0;
  __syncthreads();
  int e0 = blockIdx.x * 2048 + threadIdx.x;
  int r_[8], c_[8], rank_[8];
  int e = e0;
#pragma unroll
  for (int i = 0; i < 8; i++, e += 256) {
    if (e < EE) {
      r_[i] = ei[e];
      c_[i] = ei[EE + e];
      rank_[i] = atomicAdd(&lh[c_[i] >> BSH], 1);
    }
  }
  __syncthreads();
  for (int i = threadIdx.x; i < NB; i += 256)
    lbase[i] = lh[i] ? atomicAdd(&bcursor[i], lh[i]) : 0;
  __syncthreads();
  e = e0;
#pragma unroll
  for (int i = 0; i < 8; i++, e += 256) {
    if (e < EE) {
      int b = c_[i] >> BSH;
      ebuf[lbase[b] + rank_[i]] = make_int2(r_[i], c_[i]);
    }
  }
}

// ---------------- pass D: per-bucket node degree via LDS counters ----------------
__global__ __launch_bounds__(256) void binD_kernel(const int2* __restrict__ ebuf,
                                                   const int* __restrict__ boffs,
                                                   int* __restrict__ deg) {
  __shared__ int lcnt[512];
  int b = blockIdx.x;
  for (int i = threadIdx.x; i < 512; i += 256) lcnt[i] = 0;
  __syncthreads();
  int s = boffs[b], e = boffs[b + 1];
  for (int i = s + threadIdx.x; i < e; i += 256)
    atomicAdd(&lcnt[ebuf[i].y & 511], 1);
  __syncthreads();
  int base = b << BSH;
  for (int i = threadIdx.x; i < 512; i += 256) {
    int node = base + i;
    if (node < NN) deg[node] = lcnt[i] + 1;   // +1 self-loop
  }
}

// ---------------- node-level exclusive scan of (deg-1), 2048 elems/block ----------------
__global__ __launch_bounds__(256) void scan1_kernel(const int* __restrict__ deg,
                                                    int* __restrict__ offs,
                                                    int* __restrict__ bsums) {
  __shared__ int ts[256];
  int t = threadIdx.x;
  int base = blockIdx.x * 2048 + t * 8;
  int v[8]; int s = 0;
#pragma unroll
  for (int i = 0; i < 8; i++) {
    int idx = base + i;
    int c = (idx < NN) ? (deg[idx] - 1) : 0;
    v[i] = s; s += c;
  }
  ts[t] = s;
  __syncthreads();
  for (int off = 1; off < 256; off <<= 1) {
    int x = (t >= off) ? ts[t - off] : 0;
    __syncthreads();
    ts[t] += x;
    __syncthreads();
  }
  int excl = (t == 0) ? 0 : ts[t - 1];
  if (t == 255) bsums[blockIdx.x] = ts[255];
#pragma unroll
  for (int i = 0; i < 8; i++) {
    int idx = base + i;
    if (idx < NN) offs[idx] = excl + v[i];
  }
}

__global__ void scan2_kernel(int* bsums, int nb) {
  if (threadIdx.x == 0 && blockIdx.x == 0) {
    int s = 0;
    for (int b = 0; b < nb; b++) { int x = bsums[b]; bsums[b] = s; s += x; }
  }
}

__global__ void scan3_kernel(const int* __restrict__ deg, int* __restrict__ offs,
                             float* __restrict__ dis, const int* __restrict__ bsums) {
  int i = blockIdx.x * 256 + threadIdx.x;
  if (i >= NN) return;
  int o = offs[i] + bsums[i >> 11];
  offs[i] = o;
  dis[i] = rsqrtf((float)deg[i]);    // deg >= 1 always
  if (i == NN - 1) offs[NN] = EE;
}

// ---------------- pass C: per-bucket fine scatter with LDS cursors ----------------
__global__ __launch_bounds__(256) void binC_kernel(const int2* __restrict__ ebuf,
                                                   const int* __restrict__ boffs,
                                                   const int* __restrict__ offs,
                                                   const float* __restrict__ dis,
                                                   int2* __restrict__ csr_p) {
  __shared__ int lcur[512];
  int b = blockIdx.x;
  int base = b << BSH;
  for (int i = threadIdx.x; i < 512; i += 256) {
    int node = base + i;
    lcur[i] = (node < NN) ? offs[node] : 0;
  }
  __syncthreads();
  int s = boffs[b], e = boffs[b + 1];
  for (int i = s + threadIdx.x; i < e; i += 256) {
    int2 rc = ebuf[i];
    int slot = atomicAdd(&lcur[rc.y & 511], 1);
    csr_p[slot] = make_int2(rc.x, __float_as_int(dis[rc.x]));
  }
}

// ---------------- weight transpose + fp16 convert: Wt[m][c][k] = W_m[k][c] ----------------
__global__ void prep_kernel(const float* __restrict__ W0, const float* __restrict__ W1,
                            const float* __restrict__ W2, const float* __restrict__ gW1,
                            _Float16* __restrict__ Wt) {
  int idx = blockIdx.x * 256 + threadIdx.x;   // 4*128*128 = 65536
  int m = idx >> 14;
  int rem = idx & 16383;
  int c = rem >> 7;
  int k = rem & 127;
  const float* src = (m == 0) ? W0 : (m == 1) ? W1 : (m == 2) ? W2 : gW1;
  Wt[idx] = (_Float16)src[k * 128 + c];
}

// ---------------- MFMA GEMM: [nrows,128] @ [128,128] ----------------
template <int AF32, int MODE>
__global__ __launch_bounds__(256) void gemm_kernel(const void* __restrict__ Av,
                                                   const _Float16* __restrict__ Wt,
                                                   const float* __restrict__ bias,
                                                   _Float16* __restrict__ out,
                                                   const float* __restrict__ gW2,
                                                   const float* __restrict__ gb2,
                                                   float* __restrict__ gate, int nrows) {
  __shared__ __align__(16) _Float16 wlds[128 * 136];  // padded stride 136 halves (272 B)
  int t = threadIdx.x;
  const uint4* src = (const uint4*)Wt;
#pragma unroll
  for (int i = 0; i < 8; i++) {
    int q = t + 256 * i;
    int c = q >> 4, p = q & 15;
    *(uint4*)&wlds[c * 136 + p * 8] = src[q];
  }
  __syncthreads();

  int wid = t >> 6, l = t & 63;
  int wr0 = blockIdx.x * 64 + wid * 16;
  int row = wr0 + (l & 15);
  bool valid = row < nrows;
  f16x8 zero8 = {(_Float16)0, (_Float16)0, (_Float16)0, (_Float16)0,
                 (_Float16)0, (_Float16)0, (_Float16)0, (_Float16)0};
  f16x8 af[4];
  if (AF32) {
    const float* ap = (const float*)Av + (size_t)row * 128;
#pragma unroll
    for (int kt = 0; kt < 4; kt++) {
      if (valid) {
        const float4* p4 = (const float4*)(ap + kt * 32 + (l >> 4) * 8);
        float4 u0 = p4[0], u1 = p4[1];
        f16x8 a;
        a[0] = (_Float16)u0.x; a[1] = (_Float16)u0.y; a[2] = (_Float16)u0.z; a[3] = (_Float16)u0.w;
        a[4] = (_Float16)u1.x; a[5] = (_Float16)u1.y; a[6] = (_Float16)u1.z; a[7] = (_Float16)u1.w;
        af[kt] = a;
      } else af[kt] = zero8;
    }
  } else {
    const _Float16* ap = (const _Float16*)Av + (size_t)row * 128;
#pragma unroll
    for (int kt = 0; kt < 4; kt++)
      af[kt] = valid ? *(const f16x8*)(ap + kt * 32 + (l >> 4) * 8) : zero8;
  }

  f32x4 acc[8] = {};
  int ko = (l >> 4) * 16;
#pragma unroll
  for (int n = 0; n < 8; n++) {
    int col = n * 16 + (l & 15);
    const char* base = (const char*)wlds + col * 272;
#pragma unroll
    for (int kt = 0; kt < 4; kt++) {
      f16x8 b = *(const f16x8*)(base + kt * 64 + ko);
      acc[n] = __builtin_amdgcn_mfma_f32_16x16x32_f16(af[kt], b, acc[n], 0, 0, 0);
    }
  }

  if (MODE == 0) {
#pragma unroll
    for (int n = 0; n < 8; n++) {
      int col = n * 16 + (l & 15);
#pragma unroll
      for (int r = 0; r < 4; r++) {
        int orow = wr0 + (l >> 4) * 4 + r;
        if (orow < nrows) out[(size_t)orow * 128 + col] = (_Float16)acc[n][r];
      }
    }
  } else {
    float gp[4] = {0.f, 0.f, 0.f, 0.f};
    int c = l & 15;
#pragma unroll
    for (int n = 0; n < 8; n++) {
      int col = n * 16 + c;
      float bv = bias[col];
      float wv = gW2[col];
#pragma unroll
      for (int r = 0; r < 4; r++) gp[r] += fmaxf(acc[n][r] + bv, 0.f) * wv;
    }
#pragma unroll
    for (int m = 1; m < 16; m <<= 1) {
#pragma unroll
      for (int r = 0; r < 4; r++) gp[r] += __shfl_xor(gp[r], m);
    }
    if (c == 0) {
      float gb = gb2[0];
#pragma unroll
      for (int r = 0; r < 4; r++) {
        int orow = wr0 + (l >> 4) * 4 + r;
        if (orow < nrows) gate[orow] = gp[r] + gb;
      }
    }
  }
}

// ---------------- aggregation: wave per node, 2 edges per load (f16x4 halves) ----------------
// out[c] = relu(dc*(sum_e w_e t[src_e] + dc t[c]) + b)
__global__ __launch_bounds__(256) void agg_kernel(const _Float16* __restrict__ t,
                                                  const int* __restrict__ offs,
                                                  const int2* __restrict__ csr_p,
                                                  const float* __restrict__ dis,
                                                  const float* __restrict__ bias,
                                                  _Float16* __restrict__ out) {
  int c = blockIdx.x * 4 + (threadIdx.x >> 6);  // wave per node
  if (c >= NN) return;
  int lane = threadIdx.x & 63;
  int half = lane >> 5;        // 0: even edges, 1: odd edges
  int cl = lane & 31;          // col group: cols 4*cl .. 4*cl+3
  float dc = dis[c];
  int s = offs[c], e = offs[c + 1];
  const f16x4* t4 = (const f16x4*)t;   // row = 32 f16x4

  float a0 = 0.f, a1 = 0.f, a2 = 0.f, a3 = 0.f;
  if (half == 0) {               // self term in lo half only
    f16x4 hv = t4[(size_t)c * 32 + cl];
    a0 = dc * (float)hv[0]; a1 = dc * (float)hv[1];
    a2 = dc * (float)hv[2]; a3 = dc * (float)hv[3];
  }

  for (int k0 = s; k0 < e; k0 += 64) {
    int cnt = e - k0; if (cnt > 64) cnt = 64;
    int2 pe = csr_p[k0 + (lane < cnt ? lane : cnt - 1)];  // coop stage: lane j holds edge j
    int j = 0;
    // main: 8 edges per iteration, 4 independent row loads in flight
    for (; j + 8 <= cnt; j += 8) {
      int i0 = j + half, i1 = j + 2 + half, i2 = j + 4 + half, i3 = j + 6 + half;
      int r0 = __shfl(pe.x, i0), r1 = __shfl(pe.x, i1);
      int r2 = __shfl(pe.x, i2), r3 = __shfl(pe.x, i3);
      float w0 = __int_as_float(__shfl(pe.y, i0));
      float w1 = __int_as_float(__shfl(pe.y, i1));
      float w2 = __int_as_float(__shfl(pe.y, i2));
      float w3 = __int_as_float(__shfl(pe.y, i3));
      f16x4 v0 = t4[(size_t)r0 * 32 + cl];
      f16x4 v1 = t4[(size_t)r1 * 32 + cl];
      f16x4 v2 = t4[(size_t)r2 * 32 + cl];
      f16x4 v3 = t4[(size_t)r3 * 32 + cl];
      a0 += w0 * (float)v0[0] + w1 * (float)v1[0] + w2 * (float)v2[0] + w3 * (float)v3[0];
      a1 += w0 * (float)v0[1] + w1 * (float)v1[1] + w2 * (float)v2[1] + w3 * (float)v3[1];
      a2 += w0 * (float)v0[2] + w1 * (float)v1[2] + w2 * (float)v2[2] + w3 * (float)v3[2];
      a3 += w0 * (float)v0[3] + w1 * (float)v1[3] + w2 * (float)v2[3] + w3 * (float)v3[3];
    }
    // tail: 2 edges per iteration with guards
    for (; j < cnt; j += 2) {
      int js = j + half;
      bool act = js < cnt;
      int jc = act ? js : cnt - 1;
      int r = __shfl(pe.x, jc);
      float w = act ? __int_as_float(__shfl(pe.y, jc)) : 0.f;
      f16x4 v = t4[(size_t)r * 32 + cl];
      a0 += w * (float)v[0]; a1 += w * (float)v[1];
      a2 += w * (float)v[2]; a3 += w * (float)v[3];
    }
  }

  // combine halves
  a0 += __shfl_xor(a0, 32); a1 += __shfl_xor(a1, 32);
  a2 += __shfl_xor(a2, 32); a3 += __shfl_xor(a3, 32);

  if (half == 0) {
    const float4 bv = *(const float4*)&bias[4 * cl];
    f16x4 o;
    o[0] = (_Float16)fmaxf(a0 * dc + bv.x, 0.f);
    o[1] = (_Float16)fmaxf(a1 * dc + bv.y, 0.f);
    o[2] = (_Float16)fmaxf(a2 * dc + bv.z, 0.f);
    o[3] = (_Float16)fmaxf(a3 * dc + bv.w, 0.f);
    ((f16x4*)out)[(size_t)c * 32 + cl] = o;
  }
}

// ---------------- graph boundaries (batch sorted) ----------------
__global__ void bounds_kernel(const int* __restrict__ batch, int* gs, int* ge) {
  int i = blockIdx.x * 256 + threadIdx.x;
  if (i >= NN) return;
  int b = batch[i];
  if (i == 0 || batch[i - 1] != b) gs[b] = i;
  if (i == NN - 1 || batch[i + 1] != b) ge[b] = i + 1;
}

// ---------------- per-graph softmax + pool + MLP head ----------------
__global__ __launch_bounds__(256) void poolhead_kernel(
    const _Float16* __restrict__ h, const float* __restrict__ gate,
    const int* __restrict__ gs, const int* __restrict__ ge,
    const float* __restrict__ lW1, const float* __restrict__ lb1,
    const float* __restrict__ lW2, const float* __restrict__ lb2,
    float* __restrict__ out) {
  int g = blockIdx.x;
  int t = threadIdx.x;
  int s = gs[g], e = ge[g];
  __shared__ float red[4];
  __shared__ float pax[4][64], pay[4][64];
  __shared__ float pooled[128];
  __shared__ float hid[128];
  int wid = t >> 6, lane = t & 63;

  float m = -3.0e38f;
  for (int i = s + t; i < e; i += 256) m = fmaxf(m, gate[i]);
#pragma unroll
  for (int o = 32; o > 0; o >>= 1) m = fmaxf(m, __shfl_xor(m, o));
  if (lane == 0) red[wid] = m;
  __syncthreads();
  m = fmaxf(fmaxf(red[0], red[1]), fmaxf(red[2], red[3]));
  __syncthreads();

  float ds_ = 0.f;
  for (int i = s + t; i < e; i += 256) ds_ += __expf(gate[i] - m);
#pragma unroll
  for (int o = 32; o > 0; o >>= 1) ds_ += __shfl_xor(ds_, o);
  if (lane == 0) red[wid] = ds_;
  __syncthreads();
  float denom = red[0] + red[1] + red[2] + red[3];

  const f16x2* h2 = (const f16x2*)h;
  int cp = t & 63, q = t >> 6;
  float px = 0.f, py = 0.f;
  for (int i = s + q; i < e; i += 4) {
    float w = __expf(gate[i] - m);
    f16x2 v = h2[(size_t)i * 64 + cp];
    px += w * (float)v[0];
    py += w * (float)v[1];
  }
  pax[q][cp] = px; pay[q][cp] = py;
  __syncthreads();
  if (t < 64) {
    float inv = (e > s) ? 1.f / denom : 0.f;
    float sx = pax[0][t] + pax[1][t] + pax[2][t] + pax[3][t];
    float sy = pay[0][t] + pay[1][t] + pay[2][t] + pay[3][t];
    pooled[2 * t] = sx * inv;
    pooled[2 * t + 1] = sy * inv;
  }
  __syncthreads();

  if (t < 128) {
    float hv = lb1[t];
    for (int k = 0; k < 128; k++) hv += pooled[k] * lW1[k * 128 + t];
    hid[t] = fmaxf(hv, 0.f);
  }
  __syncthreads();

  if (t < OUTD) {
    float acc2 = lb2[t];
    for (int k = 0; k < 128; k++) acc2 += hid[k] * lW2[k * OUTD + t];
    out[g * OUTD + t] = acc2;
  }
}

extern "C" void kernel_launch(void* const* d_in, const int* in_sizes, int n_in,
                              void* d_out, int out_size, void* d_ws, size_t ws_size,
                              hipStream_t stream) {
  const float* x   = (const float*)d_in[0];
  const int*   ei  = (const int*)d_in[1];
  const int* batch = (const int*)d_in[2];
  const float* W0  = (const float*)d_in[3];
  const float* b0  = (const float*)d_in[4];
  const float* W1  = (const float*)d_in[5];
  const float* b1  = (const float*)d_in[6];
  const float* W2  = (const float*)d_in[7];
  const float* b2  = (const float*)d_in[8];
  const float* gW1 = (const float*)d_in[9];
  const float* gb1 = (const float*)d_in[10];
  const float* gW2 = (const float*)d_in[11];
  const float* gb2 = (const float*)d_in[12];
  const float* lW1 = (const float*)d_in[13];
  const float* lb1 = (const float*)d_in[14];
  const float* lW2 = (const float*)d_in[15];
  const float* lb2 = (const float*)d_in[16];
  float* out = (float*)d_out;

  char* w = (char*)d_ws;
  auto alloc = [&](size_t bytes) {
    char* p = w;
    w += (bytes + 255) & ~(size_t)255;
    return p;
  };
  _Float16* T  = (_Float16*)alloc((size_t)NN * 128 * 2);
  _Float16* HA = (_Float16*)alloc((size_t)NN * 128 * 2);
  _Float16* HB = (_Float16*)alloc((size_t)NN * 128 * 2);
  _Float16* Wt = (_Float16*)alloc((size_t)4 * 128 * 128 * 2);
  int* deg     = (int*)alloc((size_t)NN * 4);
  int* offs    = (int*)alloc((size_t)(NN + 1) * 4);
  float* dis   = (float*)alloc((size_t)NN * 4);
  int2* csr_p  = (int2*)alloc((size_t)EE * 8);
  int2* ebuf   = (int2*)alloc((size_t)EE * 8);
  float* gate  = (float*)alloc((size_t)NN * 4);
  int* bsums   = (int*)alloc(64 * 4);
  int* gs      = (int*)alloc(GG * 4);
  int* ge      = (int*)alloc(GG * 4);
  int* bcount  = (int*)alloc(NB * 4);
  int* boffs   = (int*)alloc((NB + 1) * 4);
  int* bcursor = (int*)alloc(NB * 4);

  dim3 b256(256);
  init_kernel<<<dim3(2), b256, 0, stream>>>(gs, ge, bcount, out);
  prep_kernel<<<dim3(256), b256, 0, stream>>>(W0, W1, W2, gW1, Wt);
  binA_kernel<<<dim3((EE + 2047) / 2048), b256, 0, stream>>>(ei, bcount);
  bscan_kernel<<<dim3(1), b256, 0, stream>>>(bcount, boffs, bcursor);
  binB_kernel<<<dim3((EE + 2047) / 2048), b256, 0, stream>>>(ei, bcursor, ebuf);
  binD_kernel<<<dim3(NB), b256, 0, stream>>>(ebuf, boffs, deg);
  scan1_kernel<<<dim3(49), b256, 0, stream>>>(deg, offs, bsums);
  scan2_kernel<<<dim3(1), dim3(64), 0, stream>>>(bsums, 49);
  scan3_kernel<<<dim3((NN + 255) / 256), b256, 0, stream>>>(deg, offs, dis, bsums);
  binC_kernel<<<dim3(NB), b256, 0, stream>>>(ebuf, boffs, offs, dis, csr_p);

  int gblocks = (NN + 63) / 64;
  int ablocks = (NN + 3) / 4;
  // layer 0 (A = x in f32)
  gemm_kernel<1, 0><<<dim3(gblocks), b256, 0, stream>>>(x, Wt + 0 * 16384, nullptr, T, nullptr, nullptr, nullptr, NN);
  agg_kernel<<<dim3(ablocks), b256, 0, stream>>>(T, offs, csr_p, dis, b0, HA);
  // layer 1
  gemm_kernel<0, 0><<<dim3(gblocks), b256, 0, stream>>>(HA, Wt + 1 * 16384, nullptr, T, nullptr, nullptr, nullptr, NN);
  agg_kernel<<<dim3(ablocks), b256, 0, stream>>>(T, offs, csr_p, dis, b1, HB);
  // layer 2
  gemm_kernel<0, 0><<<dim3(gblocks), b256, 0, stream>>>(HB, Wt + 2 * 16384, nullptr, T, nullptr, nullptr, nullptr, NN);
  agg_kernel<<<dim3(ablocks), b256, 0, stream>>>(T, offs, csr_p, dis, b2, HA);

  // gate network: gate = relu(HA@gW1+gb1) . gW2 + gb2  (fused epilogue, no T store)
  gemm_kernel<0, 2><<<dim3(gblocks), b256, 0, stream>>>(HA, Wt + 3 * 16384, gb1, nullptr, gW2, gb2, gate, NN);
  bounds_kernel<<<dim3((NN + 255) / 256), b256, 0, stream>>>(batch, gs, ge);
  poolhead_kernel<<<dim3(GG), b256, 0, stream>>>(HA, gate, gs, ge, lW1, lb1, lW2, lb2, out);
}

// Round 13
// 459.728 us; speedup vs baseline: 2.7153x; 1.0326x over previous
//
#include <hip/hip_runtime.h>
#include <math.h>

#define NN 100000
#define EE 1600000
#define HH 128
#define GG 512
#define OUTD 10
#define NB 196   // buckets of 512 nodes: bucket = c >> 9
#define BSH 9

typedef _Float16 f16x2 __attribute__((ext_vector_type(2)));
typedef _Float16 f16x4 __attribute__((ext_vector_type(4)));
typedef _Float16 f16x8 __attribute__((ext_vector_type(8)));
typedef float f32x4 __attribute__((ext_vector_type(4)));

// ---------------- init ----------------
__global__ void init_kernel(int* gs, int* ge, int* bcount, float* out) {
  int i = blockIdx.x * 256 + threadIdx.x;
  if (i < GG) { gs[i] = 0; ge[i] = 0; }
  if (i < NB) bcount[i] = 0;
  if (i == 0) out[GG * OUTD] = 0.0f; // the scalar second output
}

// ---------------- pass A: bucket histogram (LDS only) ----------------
__global__ __launch_bounds__(256) void binA_kernel(const int* __restrict__ ei,
                                                   int* __restrict__ bcount) {
  __shared__ int lh[NB];
  for (int i = threadIdx.x; i < NB; i += 256) lh[i] = 0;
  __syncthreads();
  int e = blockIdx.x * 2048 + threadIdx.x;
#pragma unroll
  for (int i = 0; i < 8; i++, e += 256)
    if (e < EE) atomicAdd(&lh[ei[EE + e] >> BSH], 1);
  __syncthreads();
  for (int i = threadIdx.x; i < NB; i += 256)
    if (lh[i]) atomicAdd(&bcount[i], lh[i]);
}

// ---------------- bucket scan ----------------
__global__ __launch_bounds__(256) void bscan_kernel(const int* __restrict__ bcount,
                                                    int* __restrict__ boffs,
                                                    int* __restrict__ bcursor) {
  __shared__ int ts[256];
  int t = threadIdx.x;
  int v = (t < NB) ? bcount[t] : 0;
  ts[t] = v;
  __syncthreads();
  for (int off = 1; off < 256; off <<= 1) {
    int x = (t >= off) ? ts[t - off] : 0;
    __syncthreads();
    ts[t] += x;
    __syncthreads();
  }
  int excl = (t == 0) ? 0 : ts[t - 1];
  if (t < NB) { boffs[t] = excl; bcursor[t] = excl; }
  if (t == NB - 1) boffs[NB] = excl + v;
}

// ---------------- pass B: scatter {r,c} into bucket regions (L2-friendly) ----------------
__global__ __launch_bounds__(256) void binB_kernel(const int* __restrict__ ei,
                                                   int* __restrict__ bcursor,
                                                   int2* __restrict__ ebuf) {
  __shared__ int lh[NB];
  __shared__ int lbase[NB];
  for (int i = threadIdx.x; i < NB; i += 256) lh[i] = 0;
  __syncthreads();
  int e0 = blockIdx.x * 2048 + threadIdx.x;
  int r_[8], c_[8], rank_[8];
  int e = e0;
#pragma unroll
  for (int i = 0; i < 8; i++, e += 256) {
    if (e < EE) {
      r_[i] = ei[e];
      c_[i] = ei[EE + e];
      rank_[i] = atomicAdd(&lh[c_[i] >> BSH], 1);
    }
  }
  __syncthreads();
  for (int i = threadIdx.x; i < NB; i += 256)
    lbase[i] = lh[i] ? atomicAdd(&bcursor[i], lh[i]) : 0;
  __syncthreads();
  e = e0;
#pragma unroll
  for (int i = 0; i < 8; i++, e += 256) {
    if (e < EE) {
      int b = c_[i] >> BSH;
      ebuf[lbase[b] + rank_[i]] = make_int2(r_[i], c_[i]);
    }
  }
}

// ---------------- pass D (fused): per-bucket degree count + local prefix -> offs, dis ----------------
__global__ __launch_bounds__(256) void binD_kernel(const int2* __restrict__ ebuf,
                                                   const int* __restrict__ boffs,
                                                   int* __restrict__ offs,
                                                   float* __restrict__ dis) {
  __shared__ int lcnt[512];
  __shared__ int lsum[256];
  int b = blockIdx.x, t = threadIdx.x;
  for (int i = t; i < 512; i += 256) lcnt[i] = 0;
  __syncthreads();
  int s = boffs[b], e = boffs[b + 1];
  for (int i = s + t; i < e; i += 256)
    atomicAdd(&lcnt[ebuf[i].y & 511], 1);
  __syncthreads();
  int c0 = lcnt[2 * t], c1 = lcnt[2 * t + 1];
  lsum[t] = c0 + c1;
  __syncthreads();
  for (int off = 1; off < 256; off <<= 1) {
    int x = (t >= off) ? lsum[t - off] : 0;
    __syncthreads();
    lsum[t] += x;
    __syncthreads();
  }
  int excl = (t == 0) ? 0 : lsum[t - 1];
  int base = b << BSH;
  int n0 = base + 2 * t, n1 = base + 2 * t + 1;
  if (n0 < NN) { offs[n0] = s + excl;      dis[n0] = rsqrtf((float)(c0 + 1)); }
  if (n1 < NN) { offs[n1] = s + excl + c0; dis[n1] = rsqrtf((float)(c1 + 1)); }
  if (b == 0 && t == 0) offs[NN] = EE;
}

// ---------------- pass C: per-bucket fine scatter with LDS cursors ----------------
__global__ __launch_bounds__(256) void binC_kernel(const int2* __restrict__ ebuf,
                                                   const int* __restrict__ boffs,
                                                   const int* __restrict__ offs,
                                                   const float* __restrict__ dis,
                                                   int2* __restrict__ csr_p) {
  __shared__ int lcur[512];
  int b = blockIdx.x;
  int base = b << BSH;
  for (int i = threadIdx.x; i < 512; i += 256) {
    int node = base + i;
    lcur[i] = (node < NN) ? offs[node] : 0;
  }
  __syncthreads();
  int s = boffs[b], e = boffs[b + 1];
  for (int i = s + threadIdx.x; i < e; i += 256) {
    int2 rc = ebuf[i];
    int slot = atomicAdd(&lcur[rc.y & 511], 1);
    csr_p[slot] = make_int2(rc.x, __float_as_int(dis[rc.x]));
  }
}

// ---------------- weight transpose + fp16 convert: Wt[m][c][k] = W_m[k][c] ----------------
__global__ void prep_kernel(const float* __restrict__ W0, const float* __restrict__ W1,
                            const float* __restrict__ W2, const float* __restrict__ gW1,
                            _Float16* __restrict__ Wt) {
  int idx = blockIdx.x * 256 + threadIdx.x;   // 4*128*128 = 65536
  int m = idx >> 14;
  int rem = idx & 16383;
  int c = rem >> 7;
  int k = rem & 127;
  const float* src = (m == 0) ? W0 : (m == 1) ? W1 : (m == 2) ? W2 : gW1;
  Wt[idx] = (_Float16)src[k * 128 + c];
}

// ---------------- MFMA GEMM: [nrows,128] @ [128,128] ----------------
template <int AF32, int MODE>
__global__ __launch_bounds__(256) void gemm_kernel(const void* __restrict__ Av,
                                                   const _Float16* __restrict__ Wt,
                                                   const float* __restrict__ bias,
                                                   _Float16* __restrict__ out,
                                                   const float* __restrict__ gW2,
                                                   const float* __restrict__ gb2,
                                                   float* __restrict__ gate, int nrows) {
  __shared__ __align__(16) _Float16 wlds[128 * 136];  // padded stride 136 halves (272 B)
  int t = threadIdx.x;
  const uint4* src = (const uint4*)Wt;
#pragma unroll
  for (int i = 0; i < 8; i++) {
    int q = t + 256 * i;
    int c = q >> 4, p = q & 15;
    *(uint4*)&wlds[c * 136 + p * 8] = src[q];
  }
  __syncthreads();

  int wid = t >> 6, l = t & 63;
  int wr0 = blockIdx.x * 64 + wid * 16;
  int row = wr0 + (l & 15);
  bool valid = row < nrows;
  f16x8 zero8 = {(_Float16)0, (_Float16)0, (_Float16)0, (_Float16)0,
                 (_Float16)0, (_Float16)0, (_Float16)0, (_Float16)0};
  f16x8 af[4];
  if (AF32) {
    const float* ap = (const float*)Av + (size_t)row * 128;
#pragma unroll
    for (int kt = 0; kt < 4; kt++) {
      if (valid) {
        const float4* p4 = (const float4*)(ap + kt * 32 + (l >> 4) * 8);
        float4 u0 = p4[0], u1 = p4[1];
        f16x8 a;
        a[0] = (_Float16)u0.x; a[1] = (_Float16)u0.y; a[2] = (_Float16)u0.z; a[3] = (_Float16)u0.w;
        a[4] = (_Float16)u1.x; a[5] = (_Float16)u1.y; a[6] = (_Float16)u1.z; a[7] = (_Float16)u1.w;
        af[kt] = a;
      } else af[kt] = zero8;
    }
  } else {
    const _Float16* ap = (const _Float16*)Av + (size_t)row * 128;
#pragma unroll
    for (int kt = 0; kt < 4; kt++)
      af[kt] = valid ? *(const f16x8*)(ap + kt * 32 + (l >> 4) * 8) : zero8;
  }

  f32x4 acc[8] = {};
  int ko = (l >> 4) * 16;
#pragma unroll
  for (int n = 0; n < 8; n++) {
    int col = n * 16 + (l & 15);
    const char* base = (const char*)wlds + col * 272;
#pragma unroll
    for (int kt = 0; kt < 4; kt++) {
      f16x8 b = *(const f16x8*)(base + kt * 64 + ko);
      acc[n] = __builtin_amdgcn_mfma_f32_16x16x32_f16(af[kt], b, acc[n], 0, 0, 0);
    }
  }

  if (MODE == 0) {
#pragma unroll
    for (int n = 0; n < 8; n++) {
      int col = n * 16 + (l & 15);
#pragma unroll
      for (int r = 0; r < 4; r++) {
        int orow = wr0 + (l >> 4) * 4 + r;
        if (orow < nrows) out[(size_t)orow * 128 + col] = (_Float16)acc[n][r];
      }
    }
  } else {
    float gp[4] = {0.f, 0.f, 0.f, 0.f};
    int c = l & 15;
#pragma unroll
    for (int n = 0; n < 8; n++) {
      int col = n * 16 + c;
      float bv = bias[col];
      float wv = gW2[col];
#pragma unroll
      for (int r = 0; r < 4; r++) gp[r] += fmaxf(acc[n][r] + bv, 0.f) * wv;
    }
#pragma unroll
    for (int m = 1; m < 16; m <<= 1) {
#pragma unroll
      for (int r = 0; r < 4; r++) gp[r] += __shfl_xor(gp[r], m);
    }
    if (c == 0) {
      float gb = gb2[0];
#pragma unroll
      for (int r = 0; r < 4; r++) {
        int orow = wr0 + (l >> 4) * 4 + r;
        if (orow < nrows) gate[orow] = gp[r] + gb;
      }
    }
  }
}

// ---------------- aggregation: wave per node, 2 edges per load (f16x4 halves) ----------------
// out[c] = relu(dc*(sum_e w_e t[src_e] + dc t[c]) + b)   [round-11 verified numerics]
__global__ __launch_bounds__(256) void agg_kernel(const _Float16* __restrict__ t,
                                                  const int* __restrict__ offs,
                                                  const int2* __restrict__ csr_p,
                                                  const float* __restrict__ dis,
                                                  const float* __restrict__ bias,
                                                  _Float16* __restrict__ out) {
  int c = blockIdx.x * 4 + (threadIdx.x >> 6);  // wave per node
  if (c >= NN) return;
  int lane = threadIdx.x & 63;
  int half = lane >> 5;        // 0: even edges, 1: odd edges
  int cl = lane & 31;          // col group: cols 4*cl .. 4*cl+3
  float dc = dis[c];
  int s = offs[c], e = offs[c + 1];
  const f16x4* t4 = (const f16x4*)t;   // row = 32 f16x4

  float a0 = 0.f, a1 = 0.f, a2 = 0.f, a3 = 0.f;
  if (half == 0) {               // self term in lo half only
    f16x4 hv = t4[(size_t)c * 32 + cl];
    a0 = dc * (float)hv[0]; a1 = dc * (float)hv[1];
    a2 = dc * (float)hv[2]; a3 = dc * (float)hv[3];
  }

  for (int k0 = s; k0 < e; k0 += 64) {
    int cnt = e - k0; if (cnt > 64) cnt = 64;
    int2 pe = csr_p[k0 + (lane < cnt ? lane : cnt - 1)];  // coop stage: lane j holds edge j
    int j = 0;
    // main: 8 edges per iteration, 4 independent row loads in flight
    for (; j + 8 <= cnt; j += 8) {
      int i0 = j + half, i1 = j + 2 + half, i2 = j + 4 + half, i3 = j + 6 + half;
      int r0 = __shfl(pe.x, i0), r1 = __shfl(pe.x, i1);
      int r2 = __shfl(pe.x, i2), r3 = __shfl(pe.x, i3);
      float w0 = __int_as_float(__shfl(pe.y, i0));
      float w1 = __int_as_float(__shfl(pe.y, i1));
      float w2 = __int_as_float(__shfl(pe.y, i2));
      float w3 = __int_as_float(__shfl(pe.y, i3));
      f16x4 v0 = t4[(size_t)r0 * 32 + cl];
      f16x4 v1 = t4[(size_t)r1 * 32 + cl];
      f16x4 v2 = t4[(size_t)r2 * 32 + cl];
      f16x4 v3 = t4[(size_t)r3 * 32 + cl];
      a0 += w0 * (float)v0[0] + w1 * (float)v1[0] + w2 * (float)v2[0] + w3 * (float)v3[0];
      a1 += w0 * (float)v0[1] + w1 * (float)v1[1] + w2 * (float)v2[1] + w3 * (float)v3[1];
      a2 += w0 * (float)v0[2] + w1 * (float)v1[2] + w2 * (float)v2[2] + w3 * (float)v3[2];
      a3 += w0 * (float)v0[3] + w1 * (float)v1[3] + w2 * (float)v2[3] + w3 * (float)v3[3];
    }
    // tail: 2 edges per iteration with guards
    for (; j < cnt; j += 2) {
      int js = j + half;
      bool act = js < cnt;
      int jc = act ? js : cnt - 1;
      int r = __shfl(pe.x, jc);
      float w = act ? __int_as_float(__shfl(pe.y, jc)) : 0.f;
      f16x4 v = t4[(size_t)r * 32 + cl];
      a0 += w * (float)v[0]; a1 += w * (float)v[1];
      a2 += w * (float)v[2]; a3 += w * (float)v[3];
    }
  }

  // combine halves
  a0 += __shfl_xor(a0, 32); a1 += __shfl_xor(a1, 32);
  a2 += __shfl_xor(a2, 32); a3 += __shfl_xor(a3, 32);

  if (half == 0) {
    const float4 bv = *(const float4*)&bias[4 * cl];
    f16x4 o;
    o[0] = (_Float16)fmaxf(a0 * dc + bv.x, 0.f);
    o[1] = (_Float16)fmaxf(a1 * dc + bv.y, 0.f);
    o[2] = (_Float16)fmaxf(a2 * dc + bv.z, 0.f);
    o[3] = (_Float16)fmaxf(a3 * dc + bv.w, 0.f);
    ((f16x4*)out)[(size_t)c * 32 + cl] = o;
  }
}

// ---------------- graph boundaries (batch sorted) ----------------
__global__ void bounds_kernel(const int* __restrict__ batch, int* gs, int* ge) {
  int i = blockIdx.x * 256 + threadIdx.x;
  if (i >= NN) return;
  int b = batch[i];
  if (i == 0 || batch[i - 1] != b) gs[b] = i;
  if (i == NN - 1 || batch[i + 1] != b) ge[b] = i + 1;
}

// ---------------- per-graph softmax + pool + MLP head ----------------
__global__ __launch_bounds__(256) void poolhead_kernel(
    const _Float16* __restrict__ h, const float* __restrict__ gate,
    const int* __restrict__ gs, const int* __restrict__ ge,
    const float* __restrict__ lW1, const float* __restrict__ lb1,
    const float* __restrict__ lW2, const float* __restrict__ lb2,
    float* __restrict__ out) {
  int g = blockIdx.x;
  int t = threadIdx.x;
  int s = gs[g], e = ge[g];
  __shared__ float red[4];
  __shared__ float pax[4][64], pay[4][64];
  __shared__ float pooled[128];
  __shared__ float hid[128];
  int wid = t >> 6, lane = t & 63;

  float m = -3.0e38f;
  for (int i = s + t; i < e; i += 256) m = fmaxf(m, gate[i]);
#pragma unroll
  for (int o = 32; o > 0; o >>= 1) m = fmaxf(m, __shfl_xor(m, o));
  if (lane == 0) red[wid] = m;
  __syncthreads();
  m = fmaxf(fmaxf(red[0], red[1]), fmaxf(red[2], red[3]));
  __syncthreads();

  float ds_ = 0.f;
  for (int i = s + t; i < e; i += 256) ds_ += __expf(gate[i] - m);
#pragma unroll
  for (int o = 32; o > 0; o >>= 1) ds_ += __shfl_xor(ds_, o);
  if (lane == 0) red[wid] = ds_;
  __syncthreads();
  float denom = red[0] + red[1] + red[2] + red[3];

  const f16x2* h2 = (const f16x2*)h;
  int cp = t & 63, q = t >> 6;
  float px = 0.f, py = 0.f;
  for (int i = s + q; i < e; i += 4) {
    float w = __expf(gate[i] - m);
    f16x2 v = h2[(size_t)i * 64 + cp];
    px += w * (float)v[0];
    py += w * (float)v[1];
  }
  pax[q][cp] = px; pay[q][cp] = py;
  __syncthreads();
  if (t < 64) {
    float inv = (e > s) ? 1.f / denom : 0.f;
    float sx = pax[0][t] + pax[1][t] + pax[2][t] + pax[3][t];
    float sy = pay[0][t] + pay[1][t] + pay[2][t] + pay[3][t];
    pooled[2 * t] = sx * inv;
    pooled[2 * t + 1] = sy * inv;
  }
  __syncthreads();

  if (t < 128) {
    float hv = lb1[t];
    for (int k = 0; k < 128; k++) hv += pooled[k] * lW1[k * 128 + t];
    hid[t] = fmaxf(hv, 0.f);
  }
  __syncthreads();

  if (t < OUTD) {
    float acc2 = lb2[t];
    for (int k = 0; k < 128; k++) acc2 += hid[k] * lW2[k * OUTD + t];
    out[g * OUTD + t] = acc2;
  }
}

extern "C" void kernel_launch(void* const* d_in, const int* in_sizes, int n_in,
                              void* d_out, int out_size, void* d_ws, size_t ws_size,
                              hipStream_t stream) {
  const float* x   = (const float*)d_in[0];
  const int*   ei  = (const int*)d_in[1];
  const int* batch = (const int*)d_in[2];
  const float* W0  = (const float*)d_in[3];
  const float* b0  = (const float*)d_in[4];
  const float* W1  = (const float*)d_in[5];
  const float* b1  = (const float*)d_in[6];
  const float* W2  = (const float*)d_in[7];
  const float* b2  = (const float*)d_in[8];
  const float* gW1 = (const float*)d_in[9];
  const float* gb1 = (const float*)d_in[10];
  const float* gW2 = (const float*)d_in[11];
  const float* gb2 = (const float*)d_in[12];
  const float* lW1 = (const float*)d_in[13];
  const float* lb1 = (const float*)d_in[14];
  const float* lW2 = (const float*)d_in[15];
  const float* lb2 = (const float*)d_in[16];
  float* out = (float*)d_out;

  char* w = (char*)d_ws;
  auto alloc = [&](size_t bytes) {
    char* p = w;
    w += (bytes + 255) & ~(size_t)255;
    return p;
  };
  _Float16* T  = (_Float16*)alloc((size_t)NN * 128 * 2);
  _Float16* HA = (_Float16*)alloc((size_t)NN * 128 * 2);
  _Float16* HB = (_Float16*)alloc((size_t)NN * 128 * 2);
  _Float16* Wt = (_Float16*)alloc((size_t)4 * 128 * 128 * 2);
  int* offs    = (int*)alloc((size_t)(NN + 1) * 4);
  float* dis   = (float*)alloc((size_t)NN * 4);
  int2* csr_p  = (int2*)alloc((size_t)EE * 8);
  int2* ebuf   = (int2*)alloc((size_t)EE * 8);
  float* gate  = (float*)alloc((size_t)NN * 4);
  int* gs      = (int*)alloc(GG * 4);
  int* ge      = (int*)alloc(GG * 4);
  int* bcount  = (int*)alloc(NB * 4);
  int* boffs   = (int*)alloc((NB + 1) * 4);
  int* bcursor = (int*)alloc(NB * 4);

  dim3 b256(256);
  init_kernel<<<dim3(2), b256, 0, stream>>>(gs, ge, bcount, out);
  prep_kernel<<<dim3(256), b256, 0, stream>>>(W0, W1, W2, gW1, Wt);
  binA_kernel<<<dim3((EE + 2047) / 2048), b256, 0, stream>>>(ei, bcount);
  bscan_kernel<<<dim3(1), b256, 0, stream>>>(bcount, boffs, bcursor);
  binB_kernel<<<dim3((EE + 2047) / 2048), b256, 0, stream>>>(ei, bcursor, ebuf);
  binD_kernel<<<dim3(NB), b256, 0, stream>>>(ebuf, boffs, offs, dis);
  binC_kernel<<<dim3(NB), b256, 0, stream>>>(ebuf, boffs, offs, dis, csr_p);

  int gblocks = (NN + 63) / 64;
  int ablocks = (NN + 3) / 4;
  // layer 0 (A = x in f32)
  gemm_kernel<1, 0><<<dim3(gblocks), b256, 0, stream>>>(x, Wt + 0 * 16384, nullptr, T, nullptr, nullptr, nullptr, NN);
  agg_kernel<<<dim3(ablocks), b256, 0, stream>>>(T, offs, csr_p, dis, b0, HA);
  // layer 1
  gemm_kernel<0, 0><<<dim3(gblocks), b256, 0, stream>>>(HA, Wt + 1 * 16384, nullptr, T, nullptr, nullptr, nullptr, NN);
  agg_kernel<<<dim3(ablocks), b256, 0, stream>>>(T, offs, csr_p, dis, b1, HB);
  // layer 2
  gemm_kernel<0, 0><<<dim3(gblocks), b256, 0, stream>>>(HB, Wt + 2 * 16384, nullptr, T, nullptr, nullptr, nullptr, NN);
  agg_kernel<<<dim3(ablocks), b256, 0, stream>>>(T, offs, csr_p, dis, b2, HA);

  // gate network: gate = relu(HA@gW1+gb1) . gW2 + gb2  (fused epilogue, no T store)
  gemm_kernel<0, 2><<<dim3(gblocks), b256, 0, stream>>>(HA, Wt + 3 * 16384, gb1, nullptr, gW2, gb2, gate, NN);
  bounds_kernel<<<dim3((NN + 255) / 256), b256, 0, stream>>>(batch, gs, ge);
  poolhead_kernel<<<dim3(GG), b256, 0, stream>>>(HA, gate, gs, ge, lW1, lb1, lW2, lb2, out);
}

// Round 14
// 437.180 us; speedup vs baseline: 2.8554x; 1.0516x over previous
//
#include <hip/hip_runtime.h>
#include <math.h>

#define NN 100000
#define EE 1600000
#define HH 128
#define GG 512
#define OUTD 10
#define NB 196   // buckets of 512 nodes: bucket = c >> 9
#define BSH 9
#define CAP 10240  // padded bucket capacity (mean 8192, +22 sigma)

typedef _Float16 f16x2 __attribute__((ext_vector_type(2)));
typedef _Float16 f16x4 __attribute__((ext_vector_type(4)));
typedef _Float16 f16x8 __attribute__((ext_vector_type(8)));
typedef float f32x4 __attribute__((ext_vector_type(4)));

// ---------------- init ----------------
__global__ void init_kernel(int* gs, int* ge, int* bcursor, float* out) {
  int i = blockIdx.x * 256 + threadIdx.x;
  if (i < GG) { gs[i] = 0; ge[i] = 0; }
  if (i < NB) bcursor[i] = i * CAP;
  if (i == 0) out[GG * OUTD] = 0.0f; // the scalar second output
}

// ---------------- pass B: scatter {r,c} into padded bucket regions ----------------
__global__ __launch_bounds__(256) void binB_kernel(const int* __restrict__ ei,
                                                   int* __restrict__ bcursor,
                                                   int2* __restrict__ ebuf) {
  __shared__ int lh[NB];
  __shared__ int lbase[NB];
  for (int i = threadIdx.x; i < NB; i += 256) lh[i] = 0;
  __syncthreads();
  int e0 = blockIdx.x * 2048 + threadIdx.x;
  int r_[8], c_[8], rank_[8];
  int e = e0;
#pragma unroll
  for (int i = 0; i < 8; i++, e += 256) {
    if (e < EE) {
      r_[i] = ei[e];
      c_[i] = ei[EE + e];
      rank_[i] = atomicAdd(&lh[c_[i] >> BSH], 1);
    }
  }
  __syncthreads();
  for (int i = threadIdx.x; i < NB; i += 256)
    lbase[i] = lh[i] ? atomicAdd(&bcursor[i], lh[i]) : 0;
  __syncthreads();
  e = e0;
#pragma unroll
  for (int i = 0; i < 8; i++, e += 256) {
    if (e < EE) {
      int b = c_[i] >> BSH;
      ebuf[lbase[b] + rank_[i]] = make_int2(r_[i], c_[i]);
    }
  }
}

// ---------------- pass D: per-bucket degree count + local prefix -> rng{start,end}, dis ----------------
__global__ __launch_bounds__(256) void binD_kernel(const int2* __restrict__ ebuf,
                                                   const int* __restrict__ bcursor,
                                                   int2* __restrict__ rng,
                                                   float* __restrict__ dis) {
  __shared__ int lcnt[512];
  __shared__ int lsum[256];
  int b = blockIdx.x, t = threadIdx.x;
  for (int i = t; i < 512; i += 256) lcnt[i] = 0;
  __syncthreads();
  int s = b * CAP, e = bcursor[b];
  for (int i = s + t; i < e; i += 256)
    atomicAdd(&lcnt[ebuf[i].y & 511], 1);
  __syncthreads();
  int c0 = lcnt[2 * t], c1 = lcnt[2 * t + 1];
  lsum[t] = c0 + c1;
  __syncthreads();
  for (int off = 1; off < 256; off <<= 1) {
    int x = (t >= off) ? lsum[t - off] : 0;
    __syncthreads();
    lsum[t] += x;
    __syncthreads();
  }
  int excl = (t == 0) ? 0 : lsum[t - 1];
  int base = b << BSH;
  int n0 = base + 2 * t, n1 = base + 2 * t + 1;
  int st0 = s + excl;
  if (n0 < NN) { rng[n0] = make_int2(st0, st0 + c0);       dis[n0] = rsqrtf((float)(c0 + 1)); }
  if (n1 < NN) { rng[n1] = make_int2(st0 + c0, st0 + c0 + c1); dis[n1] = rsqrtf((float)(c1 + 1)); }
}

// ---------------- pass C: per-bucket fine scatter with LDS cursors ----------------
__global__ __launch_bounds__(256) void binC_kernel(const int2* __restrict__ ebuf,
                                                   const int* __restrict__ bcursor,
                                                   const int2* __restrict__ rng,
                                                   const float* __restrict__ dis,
                                                   int2* __restrict__ csr_p) {
  __shared__ int lcur[512];
  int b = blockIdx.x;
  int base = b << BSH;
  for (int i = threadIdx.x; i < 512; i += 256) {
    int node = base + i;
    lcur[i] = (node < NN) ? rng[node].x : 0;
  }
  __syncthreads();
  int s = b * CAP, e = bcursor[b];
  for (int i = s + threadIdx.x; i < e; i += 256) {
    int2 rc = ebuf[i];
    int slot = atomicAdd(&lcur[rc.y & 511], 1);
    csr_p[slot] = make_int2(rc.x, __float_as_int(dis[rc.x]));
  }
}

// ---------------- weight transpose + fp16 convert: Wt[m][c][k] = W_m[k][c] ----------------
__global__ void prep_kernel(const float* __restrict__ W0, const float* __restrict__ W1,
                            const float* __restrict__ W2, const float* __restrict__ gW1,
                            _Float16* __restrict__ Wt) {
  int idx = blockIdx.x * 256 + threadIdx.x;   // 4*128*128 = 65536
  int m = idx >> 14;
  int rem = idx & 16383;
  int c = rem >> 7;
  int k = rem & 127;
  const float* src = (m == 0) ? W0 : (m == 1) ? W1 : (m == 2) ? W2 : gW1;
  Wt[idx] = (_Float16)src[k * 128 + c];
}

// ---------------- MFMA GEMM: [nrows,128] @ [128,128] ----------------
template <int AF32, int MODE>
__global__ __launch_bounds__(256) void gemm_kernel(const void* __restrict__ Av,
                                                   const _Float16* __restrict__ Wt,
                                                   const float* __restrict__ bias,
                                                   _Float16* __restrict__ out,
                                                   const float* __restrict__ gW2,
                                                   const float* __restrict__ gb2,
                                                   float* __restrict__ gate, int nrows) {
  __shared__ __align__(16) _Float16 wlds[128 * 136];  // padded stride 136 halves (272 B)
  int t = threadIdx.x;
  const uint4* src = (const uint4*)Wt;
#pragma unroll
  for (int i = 0; i < 8; i++) {
    int q = t + 256 * i;
    int c = q >> 4, p = q & 15;
    *(uint4*)&wlds[c * 136 + p * 8] = src[q];
  }
  __syncthreads();

  int wid = t >> 6, l = t & 63;
  int wr0 = blockIdx.x * 64 + wid * 16;
  int row = wr0 + (l & 15);
  bool valid = row < nrows;
  f16x8 zero8 = {(_Float16)0, (_Float16)0, (_Float16)0, (_Float16)0,
                 (_Float16)0, (_Float16)0, (_Float16)0, (_Float16)0};
  f16x8 af[4];
  if (AF32) {
    const float* ap = (const float*)Av + (size_t)row * 128;
#pragma unroll
    for (int kt = 0; kt < 4; kt++) {
      if (valid) {
        const float4* p4 = (const float4*)(ap + kt * 32 + (l >> 4) * 8);
        float4 u0 = p4[0], u1 = p4[1];
        f16x8 a;
        a[0] = (_Float16)u0.x; a[1] = (_Float16)u0.y; a[2] = (_Float16)u0.z; a[3] = (_Float16)u0.w;
        a[4] = (_Float16)u1.x; a[5] = (_Float16)u1.y; a[6] = (_Float16)u1.z; a[7] = (_Float16)u1.w;
        af[kt] = a;
      } else af[kt] = zero8;
    }
  } else {
    const _Float16* ap = (const _Float16*)Av + (size_t)row * 128;
#pragma unroll
    for (int kt = 0; kt < 4; kt++)
      af[kt] = valid ? *(const f16x8*)(ap + kt * 32 + (l >> 4) * 8) : zero8;
  }

  f32x4 acc[8] = {};
  int ko = (l >> 4) * 16;
#pragma unroll
  for (int n = 0; n < 8; n++) {
    int col = n * 16 + (l & 15);
    const char* base = (const char*)wlds + col * 272;
#pragma unroll
    for (int kt = 0; kt < 4; kt++) {
      f16x8 b = *(const f16x8*)(base + kt * 64 + ko);
      acc[n] = __builtin_amdgcn_mfma_f32_16x16x32_f16(af[kt], b, acc[n], 0, 0, 0);
    }
  }

  if (MODE == 0) {
#pragma unroll
    for (int n = 0; n < 8; n++) {
      int col = n * 16 + (l & 15);
#pragma unroll
      for (int r = 0; r < 4; r++) {
        int orow = wr0 + (l >> 4) * 4 + r;
        if (orow < nrows) out[(size_t)orow * 128 + col] = (_Float16)acc[n][r];
      }
    }
  } else {
    float gp[4] = {0.f, 0.f, 0.f, 0.f};
    int c = l & 15;
#pragma unroll
    for (int n = 0; n < 8; n++) {
      int col = n * 16 + c;
      float bv = bias[col];
      float wv = gW2[col];
#pragma unroll
      for (int r = 0; r < 4; r++) gp[r] += fmaxf(acc[n][r] + bv, 0.f) * wv;
    }
#pragma unroll
    for (int m = 1; m < 16; m <<= 1) {
#pragma unroll
      for (int r = 0; r < 4; r++) gp[r] += __shfl_xor(gp[r], m);
    }
    if (c == 0) {
      float gb = gb2[0];
#pragma unroll
      for (int r = 0; r < 4; r++) {
        int orow = wr0 + (l >> 4) * 4 + r;
        if (orow < nrows) gate[orow] = gp[r] + gb;
      }
    }
  }
}

// ---------------- aggregation: wave per node, 2 edges per load (f16x4 halves) ----------------
// out[c] = relu(dc*(sum_e w_e t[src_e] + dc t[c]) + b)
// Numerics: += sequence identical to round-11/13 rolled loop (16-chunk = two 8-iterations inline;
// only load issue order differs, which does not change fp results).
__global__ __launch_bounds__(256) void agg_kernel(const _Float16* __restrict__ t,
                                                  const int2* __restrict__ rng,
                                                  const int2* __restrict__ csr_p,
                                                  const float* __restrict__ dis,
                                                  const float* __restrict__ bias,
                                                  _Float16* __restrict__ out) {
  int c = blockIdx.x * 4 + (threadIdx.x >> 6);  // wave per node
  if (c >= NN) return;
  int lane = threadIdx.x & 63;
  int half = lane >> 5;        // 0: even edges, 1: odd edges
  int cl = lane & 31;          // col group: cols 4*cl .. 4*cl+3
  float dc = dis[c];
  int2 rg = rng[c];
  int s = rg.x, e = rg.y;
  const f16x4* t4 = (const f16x4*)t;   // row = 32 f16x4

  float a0 = 0.f, a1 = 0.f, a2 = 0.f, a3 = 0.f;
  if (half == 0) {               // self term in lo half only
    f16x4 hv = t4[(size_t)c * 32 + cl];
    a0 = dc * (float)hv[0]; a1 = dc * (float)hv[1];
    a2 = dc * (float)hv[2]; a3 = dc * (float)hv[3];
  }

  for (int k0 = s; k0 < e; k0 += 64) {
    int cnt = e - k0; if (cnt > 64) cnt = 64;
    int2 pe = csr_p[k0 + (lane < cnt ? lane : cnt - 1)];  // coop stage: lane j holds edge j
    int j = 0;
    // main: 16 edges per chunk -> 8 independent row loads in flight;
    // += statements match two consecutive 8-edge iterations exactly.
    for (; j + 16 <= cnt; j += 16) {
      int i0 = j + half,      i1 = j + 2 + half,  i2 = j + 4 + half,  i3 = j + 6 + half;
      int i4 = j + 8 + half,  i5 = j + 10 + half, i6 = j + 12 + half, i7 = j + 14 + half;
      int r0 = __shfl(pe.x, i0), r1 = __shfl(pe.x, i1);
      int r2 = __shfl(pe.x, i2), r3 = __shfl(pe.x, i3);
      int r4 = __shfl(pe.x, i4), r5 = __shfl(pe.x, i5);
      int r6 = __shfl(pe.x, i6), r7 = __shfl(pe.x, i7);
      float w0 = __int_as_float(__shfl(pe.y, i0));
      float w1 = __int_as_float(__shfl(pe.y, i1));
      float w2 = __int_as_float(__shfl(pe.y, i2));
      float w3 = __int_as_float(__shfl(pe.y, i3));
      float w4 = __int_as_float(__shfl(pe.y, i4));
      float w5 = __int_as_float(__shfl(pe.y, i5));
      float w6 = __int_as_float(__shfl(pe.y, i6));
      float w7 = __int_as_float(__shfl(pe.y, i7));
      f16x4 v0 = t4[(size_t)r0 * 32 + cl];
      f16x4 v1 = t4[(size_t)r1 * 32 + cl];
      f16x4 v2 = t4[(size_t)r2 * 32 + cl];
      f16x4 v3 = t4[(size_t)r3 * 32 + cl];
      f16x4 v4 = t4[(size_t)r4 * 32 + cl];
      f16x4 v5 = t4[(size_t)r5 * 32 + cl];
      f16x4 v6 = t4[(size_t)r6 * 32 + cl];
      f16x4 v7 = t4[(size_t)r7 * 32 + cl];
      a0 += w0 * (float)v0[0] + w1 * (float)v1[0] + w2 * (float)v2[0] + w3 * (float)v3[0];
      a1 += w0 * (float)v0[1] + w1 * (float)v1[1] + w2 * (float)v2[1] + w3 * (float)v3[1];
      a2 += w0 * (float)v0[2] + w1 * (float)v1[2] + w2 * (float)v2[2] + w3 * (float)v3[2];
      a3 += w0 * (float)v0[3] + w1 * (float)v1[3] + w2 * (float)v2[3] + w3 * (float)v3[3];
      a0 += w4 * (float)v4[0] + w5 * (float)v5[0] + w6 * (float)v6[0] + w7 * (float)v7[0];
      a1 += w4 * (float)v4[1] + w5 * (float)v5[1] + w6 * (float)v6[1] + w7 * (float)v7[1];
      a2 += w4 * (float)v4[2] + w5 * (float)v5[2] + w6 * (float)v6[2] + w7 * (float)v7[2];
      a3 += w4 * (float)v4[3] + w5 * (float)v5[3] + w6 * (float)v6[3] + w7 * (float)v7[3];
    }
    // 8-edge step (same body as round-13 main loop)
    for (; j + 8 <= cnt; j += 8) {
      int i0 = j + half, i1 = j + 2 + half, i2 = j + 4 + half, i3 = j + 6 + half;
      int r0 = __shfl(pe.x, i0), r1 = __shfl(pe.x, i1);
      int r2 = __shfl(pe.x, i2), r3 = __shfl(pe.x, i3);
      float w0 = __int_as_float(__shfl(pe.y, i0));
      float w1 = __int_as_float(__shfl(pe.y, i1));
      float w2 = __int_as_float(__shfl(pe.y, i2));
      float w3 = __int_as_float(__shfl(pe.y, i3));
      f16x4 v0 = t4[(size_t)r0 * 32 + cl];
      f16x4 v1 = t4[(size_t)r1 * 32 + cl];
      f16x4 v2 = t4[(size_t)r2 * 32 + cl];
      f16x4 v3 = t4[(size_t)r3 * 32 + cl];
      a0 += w0 * (float)v0[0] + w1 * (float)v1[0] + w2 * (float)v2[0] + w3 * (float)v3[0];
      a1 += w0 * (float)v0[1] + w1 * (float)v1[1] + w2 * (float)v2[1] + w3 * (float)v3[1];
      a2 += w0 * (float)v0[2] + w1 * (float)v1[2] + w2 * (float)v2[2] + w3 * (float)v3[2];
      a3 += w0 * (float)v0[3] + w1 * (float)v1[3] + w2 * (float)v2[3] + w3 * (float)v3[3];
    }
    // tail: 2 edges per iteration with guards
    for (; j < cnt; j += 2) {
      int js = j + half;
      bool act = js < cnt;
      int jc = act ? js : cnt - 1;
      int r = __shfl(pe.x, jc);
      float w = act ? __int_as_float(__shfl(pe.y, jc)) : 0.f;
      f16x4 v = t4[(size_t)r * 32 + cl];
      a0 += w * (float)v[0]; a1 += w * (float)v[1];
      a2 += w * (float)v[2]; a3 += w * (float)v[3];
    }
  }

  // combine halves
  a0 += __shfl_xor(a0, 32); a1 += __shfl_xor(a1, 32);
  a2 += __shfl_xor(a2, 32); a3 += __shfl_xor(a3, 32);

  if (half == 0) {
    const float4 bv = *(const float4*)&bias[4 * cl];
    f16x4 o;
    o[0] = (_Float16)fmaxf(a0 * dc + bv.x, 0.f);
    o[1] = (_Float16)fmaxf(a1 * dc + bv.y, 0.f);
    o[2] = (_Float16)fmaxf(a2 * dc + bv.z, 0.f);
    o[3] = (_Float16)fmaxf(a3 * dc + bv.w, 0.f);
    ((f16x4*)out)[(size_t)c * 32 + cl] = o;
  }
}

// ---------------- graph boundaries (batch sorted) ----------------
__global__ void bounds_kernel(const int* __restrict__ batch, int* gs, int* ge) {
  int i = blockIdx.x * 256 + threadIdx.x;
  if (i >= NN) return;
  int b = batch[i];
  if (i == 0 || batch[i - 1] != b) gs[b] = i;
  if (i == NN - 1 || batch[i + 1] != b) ge[b] = i + 1;
}

// ---------------- per-graph softmax + pool + MLP head ----------------
__global__ __launch_bounds__(256) void poolhead_kernel(
    const _Float16* __restrict__ h, const float* __restrict__ gate,
    const int* __restrict__ gs, const int* __restrict__ ge,
    const float* __restrict__ lW1, const float* __restrict__ lb1,
    const float* __restrict__ lW2, const float* __restrict__ lb2,
    float* __restrict__ out) {
  int g = blockIdx.x;
  int t = threadIdx.x;
  int s = gs[g], e = ge[g];
  __shared__ float red[4];
  __shared__ float pax[4][64], pay[4][64];
  __shared__ float pooled[128];
  __shared__ float hid[128];
  int wid = t >> 6, lane = t & 63;

  float m = -3.0e38f;
  for (int i = s + t; i < e; i += 256) m = fmaxf(m, gate[i]);
#pragma unroll
  for (int o = 32; o > 0; o >>= 1) m = fmaxf(m, __shfl_xor(m, o));
  if (lane == 0) red[wid] = m;
  __syncthreads();
  m = fmaxf(fmaxf(red[0], red[1]), fmaxf(red[2], red[3]));
  __syncthreads();

  float ds_ = 0.f;
  for (int i = s + t; i < e; i += 256) ds_ += __expf(gate[i] - m);
#pragma unroll
  for (int o = 32; o > 0; o >>= 1) ds_ += __shfl_xor(ds_, o);
  if (lane == 0) red[wid] = ds_;
  __syncthreads();
  float denom = red[0] + red[1] + red[2] + red[3];

  const f16x2* h2 = (const f16x2*)h;
  int cp = t & 63, q = t >> 6;
  float px = 0.f, py = 0.f;
  for (int i = s + q; i < e; i += 4) {
    float w = __expf(gate[i] - m);
    f16x2 v = h2[(size_t)i * 64 + cp];
    px += w * (float)v[0];
    py += w * (float)v[1];
  }
  pax[q][cp] = px; pay[q][cp] = py;
  __syncthreads();
  if (t < 64) {
    float inv = (e > s) ? 1.f / denom : 0.f;
    float sx = pax[0][t] + pax[1][t] + pax[2][t] + pax[3][t];
    float sy = pay[0][t] + pay[1][t] + pay[2][t] + pay[3][t];
    pooled[2 * t] = sx * inv;
    pooled[2 * t + 1] = sy * inv;
  }
  __syncthreads();

  if (t < 128) {
    float hv = lb1[t];
    for (int k = 0; k < 128; k++) hv += pooled[k] * lW1[k * 128 + t];
    hid[t] = fmaxf(hv, 0.f);
  }
  __syncthreads();

  if (t < OUTD) {
    float acc2 = lb2[t];
    for (int k = 0; k < 128; k++) acc2 += hid[k] * lW2[k * OUTD + t];
    out[g * OUTD + t] = acc2;
  }
}

extern "C" void kernel_launch(void* const* d_in, const int* in_sizes, int n_in,
                              void* d_out, int out_size, void* d_ws, size_t ws_size,
                              hipStream_t stream) {
  const float* x   = (const float*)d_in[0];
  const int*   ei  = (const int*)d_in[1];
  const int* batch = (const int*)d_in[2];
  const float* W0  = (const float*)d_in[3];
  const float* b0  = (const float*)d_in[4];
  const float* W1  = (const float*)d_in[5];
  const float* b1  = (const float*)d_in[6];
  const float* W2  = (const float*)d_in[7];
  const float* b2  = (const float*)d_in[8];
  const float* gW1 = (const float*)d_in[9];
  const float* gb1 = (const float*)d_in[10];
  const float* gW2 = (const float*)d_in[11];
  const float* gb2 = (const float*)d_in[12];
  const float* lW1 = (const float*)d_in[13];
  const float* lb1 = (const float*)d_in[14];
  const float* lW2 = (const float*)d_in[15];
  const float* lb2 = (const float*)d_in[16];
  float* out = (float*)d_out;

  char* w = (char*)d_ws;
  auto alloc = [&](size_t bytes) {
    char* p = w;
    w += (bytes + 255) & ~(size_t)255;
    return p;
  };
  _Float16* T  = (_Float16*)alloc((size_t)NN * 128 * 2);
  _Float16* HA = (_Float16*)alloc((size_t)NN * 128 * 2);
  _Float16* HB = (_Float16*)alloc((size_t)NN * 128 * 2);
  _Float16* Wt = (_Float16*)alloc((size_t)4 * 128 * 128 * 2);
  int2* rng    = (int2*)alloc((size_t)NN * 8);
  float* dis   = (float*)alloc((size_t)NN * 4);
  int2* csr_p  = (int2*)alloc((size_t)NB * CAP * 8);
  int2* ebuf   = (int2*)alloc((size_t)NB * CAP * 8);
  float* gate  = (float*)alloc((size_t)NN * 4);
  int* gs      = (int*)alloc(GG * 4);
  int* ge      = (int*)alloc(GG * 4);
  int* bcursor = (int*)alloc(NB * 4);

  dim3 b256(256);
  init_kernel<<<dim3(2), b256, 0, stream>>>(gs, ge, bcursor, out);
  prep_kernel<<<dim3(256), b256, 0, stream>>>(W0, W1, W2, gW1, Wt);
  binB_kernel<<<dim3((EE + 2047) / 2048), b256, 0, stream>>>(ei, bcursor, ebuf);
  binD_kernel<<<dim3(NB), b256, 0, stream>>>(ebuf, bcursor, rng, dis);
  binC_kernel<<<dim3(NB), b256, 0, stream>>>(ebuf, bcursor, rng, dis, csr_p);

  int gblocks = (NN + 63) / 64;
  int ablocks = (NN + 3) / 4;
  // layer 0 (A = x in f32)
  gemm_kernel<1, 0><<<dim3(gblocks), b256, 0, stream>>>(x, Wt + 0 * 16384, nullptr, T, nullptr, nullptr, nullptr, NN);
  agg_kernel<<<dim3(ablocks), b256, 0, stream>>>(T, rng, csr_p, dis, b0, HA);
  // layer 1
  gemm_kernel<0, 0><<<dim3(gblocks), b256, 0, stream>>>(HA, Wt + 1 * 16384, nullptr, T, nullptr, nullptr, nullptr, NN);
  agg_kernel<<<dim3(ablocks), b256, 0, stream>>>(T, rng, csr_p, dis, b1, HB);
  // layer 2
  gemm_kernel<0, 0><<<dim3(gblocks), b256, 0, stream>>>(HB, Wt + 2 * 16384, nullptr, T, nullptr, nullptr, nullptr, NN);
  agg_kernel<<<dim3(ablocks), b256, 0, stream>>>(T, rng, csr_p, dis, b2, HA);

  // gate network: gate = relu(HA@gW1+gb1) . gW2 + gb2  (fused epilogue, no T store)
  gemm_kernel<0, 2><<<dim3(gblocks), b256, 0, stream>>>(HA, Wt + 3 * 16384, gb1, nullptr, gW2, gb2, gate, NN);
  bounds_kernel<<<dim3((NN + 255) / 256), b256, 0, stream>>>(batch, gs, ge);
  poolhead_kernel<<<dim3(GG), b256, 0, stream>>>(HA, gate, gs, ge, lW1, lb1, lW2, lb2, out);
}